// Round 1
// baseline (4203.779 us; speedup 1.0000x reference)
//
#include <hip/hip_runtime.h>
#include <hip/hip_bf16.h>

// GNN decoder: 2x (GCNConv -> BatchNorm[-> ReLU]) on N=100000 nodes, E=1.6M edges.
// f32 baseline. Bias cancels inside BatchNorm (mean-subtraction) so b1/b2 skipped.
// BN1+ReLU fused into GEMM2 input load. Self-loop term fused into GEMM epilogues.

#define IN_C 128
#define HID_C 128
#define OUT_C2 64
#define KDIM 128
#define KB 64
#define BN_EPS 1e-5f

__global__ void zero_kernel(float* __restrict__ p, int n) {
    int i = blockIdx.x * blockDim.x + threadIdx.x;
    if (i < n) p[i] = 0.0f;
}

__global__ void degree_kernel(const int* __restrict__ dst, float* __restrict__ deg, int E) {
    int i = blockIdx.x * blockDim.x + threadIdx.x;
    int stride = gridDim.x * blockDim.x;
    for (; i < E; i += stride)
        atomicAdd(&deg[dst[i]], 1.0f);
}

__global__ void dinv_kernel(float* __restrict__ deg, int N) {
    int i = blockIdx.x * blockDim.x + threadIdx.x;
    if (i < N) deg[i] = rsqrtf(deg[i] + 1.0f);  // +1 self-loop; always > 0
}

__global__ void norm_kernel(const int* __restrict__ src, const int* __restrict__ dst,
                            const float* __restrict__ dinv, float* __restrict__ nrm, int E) {
    int i = blockIdx.x * blockDim.x + threadIdx.x;
    int stride = gridDim.x * blockDim.x;
    for (; i < E; i += stride)
        nrm[i] = dinv[src[i]] * dinv[dst[i]];
}

// Y = X @ W  (X: [N,128], W: [128,OC], row-major). Also writes Yself = dinv^2 * Y
// (self-loop init of the aggregation buffer). If BN_IN: X is BN1+ReLU'd on load.
template <int OC, bool BN_IN>
__global__ __launch_bounds__(256) void gemm_kernel(
    const float* __restrict__ X, const float* __restrict__ W,
    float* __restrict__ Y, float* __restrict__ Yself,
    const float* __restrict__ dinv,
    const float* __restrict__ stats, const float* __restrict__ gamma,
    const float* __restrict__ beta, int N)
{
    constexpr int LANE_COLS = OC / 4;          // 32 (OC=128) or 16 (OC=64)
    constexpr int THREAD_ROWS = 256 / LANE_COLS;
    constexpr int ROWS = THREAD_ROWS * 4;      // 32 or 64

    __shared__ float Wl[KB * OC];
    __shared__ float Xl[ROWS][KB + 4];
    __shared__ __align__(16) float sc[KDIM];
    __shared__ __align__(16) float sh[KDIM];

    const int tid = threadIdx.x;
    const int rbase = blockIdx.x * ROWS;

    if constexpr (BN_IN) {
        if (tid < KDIM) {
            float invN = 1.0f / (float)N;
            float mu = stats[tid] * invN;
            float var = stats[KDIM + tid] * invN - mu * mu;
            float s = rsqrtf(var + BN_EPS) * gamma[tid];
            sc[tid] = s;
            sh[tid] = beta[tid] - mu * s;
        }
        __syncthreads();
    }

    const int cg = tid % LANE_COLS;
    const int rg = tid / LANE_COLS;
    const int c0 = cg * 4;
    float acc[4][4] = {};

    for (int kb = 0; kb < KDIM; kb += KB) {
        // stage W chunk [kb..kb+KB) x OC  (contiguous)
        for (int i = tid * 4; i < KB * OC; i += 256 * 4)
            *(float4*)&Wl[i] = *(const float4*)&W[kb * OC + i];
        // stage X chunk rows [rbase..rbase+ROWS), cols [kb..kb+KB)
        for (int i = tid * 4; i < ROWS * KB; i += 256 * 4) {
            int r = i / KB, k = i % KB;
            int gr = rbase + r;
            float4 v = make_float4(0.f, 0.f, 0.f, 0.f);
            if (gr < N) v = *(const float4*)&X[(size_t)gr * KDIM + kb + k];
            if constexpr (BN_IN) {
                float4 s4 = *(const float4*)&sc[kb + k];
                float4 h4 = *(const float4*)&sh[kb + k];
                v.x = fmaxf(fmaf(v.x, s4.x, h4.x), 0.f);
                v.y = fmaxf(fmaf(v.y, s4.y, h4.y), 0.f);
                v.z = fmaxf(fmaf(v.z, s4.z, h4.z), 0.f);
                v.w = fmaxf(fmaf(v.w, s4.w, h4.w), 0.f);
            }
            *(float4*)&Xl[r][k] = v;
        }
        __syncthreads();

        for (int k = 0; k < KB; ++k) {
            float4 w = *(float4*)&Wl[k * OC + c0];
            #pragma unroll
            for (int j = 0; j < 4; ++j) {
                float xv = Xl[rg * 4 + j][k];
                acc[j][0] = fmaf(xv, w.x, acc[j][0]);
                acc[j][1] = fmaf(xv, w.y, acc[j][1]);
                acc[j][2] = fmaf(xv, w.z, acc[j][2]);
                acc[j][3] = fmaf(xv, w.w, acc[j][3]);
            }
        }
        __syncthreads();
    }

    #pragma unroll
    for (int j = 0; j < 4; ++j) {
        int gr = rbase + rg * 4 + j;
        if (gr < N) {
            float4 o = make_float4(acc[j][0], acc[j][1], acc[j][2], acc[j][3]);
            *(float4*)&Y[(size_t)gr * OC + c0] = o;
            float di = dinv[gr];
            float w2 = di * di;
            float4 o2 = make_float4(o.x * w2, o.y * w2, o.z * w2, o.w * w2);
            *(float4*)&Yself[(size_t)gr * OC + c0] = o2;
        }
    }
}

// Edge scatter: agg[dst] += h[src] * nrm   (C/4 threads per edge, float4 lanes)
template <int C>
__global__ void scatter_kernel(const float* __restrict__ h, const int* __restrict__ src,
                               const int* __restrict__ dst, const float* __restrict__ nrm,
                               float* __restrict__ agg, int E)
{
    constexpr int TPE = C / 4;
    int t = blockIdx.x * blockDim.x + threadIdx.x;
    int lane = t % TPE;
    int e = t / TPE;
    int estride = (gridDim.x * blockDim.x) / TPE;
    for (; e < E; e += estride) {
        int s = src[e], d = dst[e];
        float w = nrm[e];
        float4 v = *(const float4*)&h[(size_t)s * C + lane * 4];
        float* out = &agg[(size_t)d * C + lane * 4];
        atomicAdd(out + 0, v.x * w);
        atomicAdd(out + 1, v.y * w);
        atomicAdd(out + 2, v.z * w);
        atomicAdd(out + 3, v.w * w);
    }
}

// Per-channel sum & sumsq over rows -> sums[0..C) = sum, sums[C..2C) = sumsq
template <int C>
__global__ __launch_bounds__(256) void stats_kernel(const float* __restrict__ h,
                                                    float* __restrict__ sums, int N)
{
    constexpr int CG = C / 4;
    constexpr int RPB = 256 / CG;
    __shared__ float red[RPB][CG][8];
    int tid = threadIdx.x;
    int cg = tid % CG, rg = tid / CG;
    int c0 = cg * 4;
    float4 s = make_float4(0.f, 0.f, 0.f, 0.f);
    float4 q = make_float4(0.f, 0.f, 0.f, 0.f);
    for (int r = blockIdx.x * RPB + rg; r < N; r += gridDim.x * RPB) {
        float4 v = *(const float4*)&h[(size_t)r * C + c0];
        s.x += v.x; s.y += v.y; s.z += v.z; s.w += v.w;
        q.x = fmaf(v.x, v.x, q.x); q.y = fmaf(v.y, v.y, q.y);
        q.z = fmaf(v.z, v.z, q.z); q.w = fmaf(v.w, v.w, q.w);
    }
    float* rr = red[rg][cg];
    rr[0] = s.x; rr[1] = s.y; rr[2] = s.z; rr[3] = s.w;
    rr[4] = q.x; rr[5] = q.y; rr[6] = q.z; rr[7] = q.w;
    __syncthreads();
    if (rg == 0) {
        float a[8];
        #pragma unroll
        for (int i = 0; i < 8; ++i) a[i] = red[0][cg][i];
        for (int r2 = 1; r2 < RPB; ++r2)
            #pragma unroll
            for (int i = 0; i < 8; ++i) a[i] += red[r2][cg][i];
        atomicAdd(&sums[c0 + 0], a[0]); atomicAdd(&sums[c0 + 1], a[1]);
        atomicAdd(&sums[c0 + 2], a[2]); atomicAdd(&sums[c0 + 3], a[3]);
        atomicAdd(&sums[C + c0 + 0], a[4]); atomicAdd(&sums[C + c0 + 1], a[5]);
        atomicAdd(&sums[C + c0 + 2], a[6]); atomicAdd(&sums[C + c0 + 3], a[7]);
    }
}

template <int C, bool RELU>
__global__ void bn_apply_kernel(const float* __restrict__ in, float* __restrict__ out,
                                const float* __restrict__ sums, const float* __restrict__ gamma,
                                const float* __restrict__ beta, int N)
{
    int total = N * (C / 4);
    int i = blockIdx.x * blockDim.x + threadIdx.x;
    int stride = gridDim.x * blockDim.x;
    float invN = 1.0f / (float)N;
    for (; i < total; i += stride) {
        int c0 = (i * 4) % C;
        float4 v = *(const float4*)&in[(size_t)i * 4];
        float4 sm = *(const float4*)&sums[c0];
        float4 sq = *(const float4*)&sums[C + c0];
        float4 g = *(const float4*)&gamma[c0];
        float4 b = *(const float4*)&beta[c0];
        float mu, var, scl;
        mu = sm.x * invN; var = sq.x * invN - mu * mu; scl = rsqrtf(var + BN_EPS) * g.x;
        v.x = fmaf(v.x - mu, scl, b.x);
        mu = sm.y * invN; var = sq.y * invN - mu * mu; scl = rsqrtf(var + BN_EPS) * g.y;
        v.y = fmaf(v.y - mu, scl, b.y);
        mu = sm.z * invN; var = sq.z * invN - mu * mu; scl = rsqrtf(var + BN_EPS) * g.z;
        v.z = fmaf(v.z - mu, scl, b.z);
        mu = sm.w * invN; var = sq.w * invN - mu * mu; scl = rsqrtf(var + BN_EPS) * g.w;
        v.w = fmaf(v.w - mu, scl, b.w);
        if (RELU) {
            v.x = fmaxf(v.x, 0.f); v.y = fmaxf(v.y, 0.f);
            v.z = fmaxf(v.z, 0.f); v.w = fmaxf(v.w, 0.f);
        }
        *(float4*)&out[(size_t)i * 4] = v;
    }
}

extern "C" void kernel_launch(void* const* d_in, const int* in_sizes, int n_in,
                              void* d_out, int out_size, void* d_ws, size_t ws_size,
                              hipStream_t stream) {
    const float* x      = (const float*)d_in[0];
    const int*   ei     = (const int*)d_in[1];
    const float* W1     = (const float*)d_in[2];
    // d_in[3] = b1: cancels in BN1 (mean subtraction) -> skipped
    const float* gamma1 = (const float*)d_in[4];
    const float* beta1  = (const float*)d_in[5];
    const float* W2     = (const float*)d_in[6];
    // d_in[7] = b2: cancels in BN2 -> skipped
    const float* gamma2 = (const float*)d_in[8];
    const float* beta2  = (const float*)d_in[9];

    const int N = in_sizes[0] / IN_C;   // 100000
    const int E = in_sizes[1] / 2;      // 1600000
    const int* src = ei;
    const int* dst = ei + E;

    float* ws = (float*)d_ws;
    // ws layout (floats): [stats1 256][stats2 128][dinv N][norm E][bufA N*128][bufB N*128]
    float* stats1 = ws;
    float* stats2 = ws + 256;
    float* dinv   = ws + 384;
    float* nrm    = dinv + N;            // offset 384+N (mult of 4 -> 16B aligned)
    float* bufA   = nrm + E;
    float* bufB   = bufA + (size_t)N * HID_C;
    float* h2     = bufA;                       // layer2 reuses bufA (N*64)
    float* agg2   = bufA + (size_t)N * OUT_C2;  // second half of bufA

    // zero: stats1+stats2+deg  (contiguous prefix)
    int zn = 384 + N;
    zero_kernel<<<(zn + 255) / 256, 256, 0, stream>>>(ws, zn);
    degree_kernel<<<2048, 256, 0, stream>>>(dst, dinv, E);
    dinv_kernel<<<(N + 255) / 256, 256, 0, stream>>>(dinv, N);
    norm_kernel<<<2048, 256, 0, stream>>>(src, dst, dinv, nrm, E);

    // Layer 1: h1 = x@W1 (bufA); bufB = dinv^2*h1 (self-loop init)
    gemm_kernel<HID_C, false><<<(N + 31) / 32, 256, 0, stream>>>(
        x, W1, bufA, bufB, dinv, nullptr, nullptr, nullptr, N);
    scatter_kernel<HID_C><<<2048, 256, 0, stream>>>(bufA, src, dst, nrm, bufB, E);
    stats_kernel<HID_C><<<256, 256, 0, stream>>>(bufB, stats1, N);

    // Layer 2: h2 = relu(bn1(bufB)) @ W2 (BN fused in load); agg2 = dinv^2*h2
    gemm_kernel<OUT_C2, true><<<(N + 63) / 64, 256, 0, stream>>>(
        bufB, W2, h2, agg2, dinv, stats1, gamma1, beta1, N);
    scatter_kernel<OUT_C2><<<2048, 256, 0, stream>>>(h2, src, dst, nrm, agg2, E);
    stats_kernel<OUT_C2><<<256, 256, 0, stream>>>(agg2, stats2, N);

    // BN2 -> d_out
    bn_apply_kernel<OUT_C2, false><<<2048, 256, 0, stream>>>(
        agg2, (float*)d_out, stats2, gamma2, beta2, N);
}

// Round 2
// 595.415 us; speedup vs baseline: 7.0603x; 7.0603x over previous
//
#include <hip/hip_runtime.h>
#include <hip/hip_bf16.h>

// GNN decoder: 2x (GCNConv -> BatchNorm[-> ReLU]) on N=100000 nodes, E=1.6M edges.
// Round 2: CSR-by-dst gather aggregation replaces f32 atomic scatter (round-1
// profile: scatter = 95% of time, 3.2 GB atomic RMW traffic vs 51 MB useful).
// Bias cancels inside BatchNorm -> b1/b2 skipped. BN1+ReLU fused into GEMM2 load.
// Self-loop term fused into the aggregate kernel (GEMM writes one buffer only).

#define IN_C 128
#define HID_C 128
#define OUT_C2 64
#define KDIM 128
#define KB 64
#define BN_EPS 1e-5f

__global__ void zero_f_kernel(float* __restrict__ p, int n) {
    int i = blockIdx.x * blockDim.x + threadIdx.x;
    if (i < n) p[i] = 0.0f;
}

__global__ void zero_i_kernel(int* __restrict__ p, int n) {
    int i = blockIdx.x * blockDim.x + threadIdx.x;
    if (i < n) p[i] = 0;
}

__global__ void degree_kernel(const int* __restrict__ dst, int* __restrict__ deg, int E) {
    int i = blockIdx.x * blockDim.x + threadIdx.x;
    int stride = gridDim.x * blockDim.x;
    for (; i < E; i += stride)
        atomicAdd(&deg[dst[i]], 1);
}

__global__ void dinv_kernel(const int* __restrict__ deg, float* __restrict__ dinv, int N) {
    int i = blockIdx.x * blockDim.x + threadIdx.x;
    if (i < N) dinv[i] = rsqrtf((float)deg[i] + 1.0f);  // +1 self-loop; always > 0
}

// ---- exclusive scan of deg[N] -> row_ptr[N] (+ tile sums), 1024-elem tiles ----
__global__ __launch_bounds__(256) void scan1_kernel(const int* __restrict__ in,
                                                    int* __restrict__ out,
                                                    int* __restrict__ tilesums, int n)
{
    __shared__ int sdata[256];
    int t = threadIdx.x;
    int idx = blockIdx.x * 1024 + t * 4;
    int4 v = make_int4(0, 0, 0, 0);
    if (idx + 3 < n) v = *(const int4*)&in[idx];
    else {
        if (idx < n)     v.x = in[idx];
        if (idx + 1 < n) v.y = in[idx + 1];
        if (idx + 2 < n) v.z = in[idx + 2];
        if (idx + 3 < n) v.w = in[idx + 3];
    }
    int s1 = v.x, s2 = s1 + v.y, s3 = s2 + v.z, s4 = s3 + v.w;
    sdata[t] = s4;
    __syncthreads();
    for (int off = 1; off < 256; off <<= 1) {
        int val = (t >= off) ? sdata[t - off] : 0;
        __syncthreads();
        sdata[t] += val;
        __syncthreads();
    }
    int prev = sdata[t] - s4;  // exclusive prefix of this thread's 4-chunk
    if (idx < n)     out[idx]     = prev;
    if (idx + 1 < n) out[idx + 1] = prev + s1;
    if (idx + 2 < n) out[idx + 2] = prev + s2;
    if (idx + 3 < n) out[idx + 3] = prev + s3;
    if (t == 255) tilesums[blockIdx.x] = sdata[255];
}

__global__ void scan2_kernel(int* __restrict__ ts, int nt) {
    __shared__ int sdata[256];
    int t = threadIdx.x;
    int v = (t < nt) ? ts[t] : 0;
    sdata[t] = v;
    __syncthreads();
    for (int off = 1; off < 256; off <<= 1) {
        int val = (t >= off) ? sdata[t - off] : 0;
        __syncthreads();
        sdata[t] += val;
        __syncthreads();
    }
    if (t < nt) ts[t] = sdata[t] - v;  // exclusive
}

__global__ void scan3_kernel(int* __restrict__ row_ptr, int* __restrict__ cursor,
                             const int* __restrict__ ts, int n, int total) {
    int i = blockIdx.x * blockDim.x + threadIdx.x;
    if (i == 0) row_ptr[n] = total;
    if (i < n) {
        int rp = row_ptr[i] + ts[i >> 10];
        row_ptr[i] = rp;
        cursor[i] = rp;
    }
}

__global__ void csr_build_kernel(const int* __restrict__ src, const int* __restrict__ dst,
                                 int* __restrict__ cursor, int* __restrict__ csr_src, int E) {
    int i = blockIdx.x * blockDim.x + threadIdx.x;
    int stride = gridDim.x * blockDim.x;
    for (; i < E; i += stride) {
        int pos = atomicAdd(&cursor[dst[i]], 1);
        csr_src[pos] = src[i];
    }
}

// Y = X @ W  (X: [N,128], W: [128,OC], row-major). If BN_IN: X is BN1+ReLU'd on load.
template <int OC, bool BN_IN>
__global__ __launch_bounds__(256) void gemm_kernel(
    const float* __restrict__ X, const float* __restrict__ W,
    float* __restrict__ Y,
    const float* __restrict__ stats, const float* __restrict__ gamma,
    const float* __restrict__ beta, int N)
{
    constexpr int LANE_COLS = OC / 4;          // 32 (OC=128) or 16 (OC=64)
    constexpr int THREAD_ROWS = 256 / LANE_COLS;
    constexpr int ROWS = THREAD_ROWS * 4;      // 32 or 64

    __shared__ float Wl[KB * OC];
    __shared__ float Xl[ROWS][KB + 4];
    __shared__ __align__(16) float sc[KDIM];
    __shared__ __align__(16) float sh[KDIM];

    const int tid = threadIdx.x;
    const int rbase = blockIdx.x * ROWS;

    if constexpr (BN_IN) {
        if (tid < KDIM) {
            float invN = 1.0f / (float)N;
            float mu = stats[tid] * invN;
            float var = stats[KDIM + tid] * invN - mu * mu;
            float s = rsqrtf(var + BN_EPS) * gamma[tid];
            sc[tid] = s;
            sh[tid] = beta[tid] - mu * s;
        }
        __syncthreads();
    }

    const int cg = tid % LANE_COLS;
    const int rg = tid / LANE_COLS;
    const int c0 = cg * 4;
    float acc[4][4] = {};

    for (int kb = 0; kb < KDIM; kb += KB) {
        for (int i = tid * 4; i < KB * OC; i += 256 * 4)
            *(float4*)&Wl[i] = *(const float4*)&W[kb * OC + i];
        for (int i = tid * 4; i < ROWS * KB; i += 256 * 4) {
            int r = i / KB, k = i % KB;
            int gr = rbase + r;
            float4 v = make_float4(0.f, 0.f, 0.f, 0.f);
            if (gr < N) v = *(const float4*)&X[(size_t)gr * KDIM + kb + k];
            if constexpr (BN_IN) {
                float4 s4 = *(const float4*)&sc[kb + k];
                float4 h4 = *(const float4*)&sh[kb + k];
                v.x = fmaxf(fmaf(v.x, s4.x, h4.x), 0.f);
                v.y = fmaxf(fmaf(v.y, s4.y, h4.y), 0.f);
                v.z = fmaxf(fmaf(v.z, s4.z, h4.z), 0.f);
                v.w = fmaxf(fmaf(v.w, s4.w, h4.w), 0.f);
            }
            *(float4*)&Xl[r][k] = v;
        }
        __syncthreads();

        for (int k = 0; k < KB; ++k) {
            float4 w = *(float4*)&Wl[k * OC + c0];
            #pragma unroll
            for (int j = 0; j < 4; ++j) {
                float xv = Xl[rg * 4 + j][k];
                acc[j][0] = fmaf(xv, w.x, acc[j][0]);
                acc[j][1] = fmaf(xv, w.y, acc[j][1]);
                acc[j][2] = fmaf(xv, w.z, acc[j][2]);
                acc[j][3] = fmaf(xv, w.w, acc[j][3]);
            }
        }
        __syncthreads();
    }

    #pragma unroll
    for (int j = 0; j < 4; ++j) {
        int gr = rbase + rg * 4 + j;
        if (gr < N)
            *(float4*)&Y[(size_t)gr * OC + c0] =
                make_float4(acc[j][0], acc[j][1], acc[j][2], acc[j][3]);
    }
}

// out[d] = dinv[d]^2 * h[d] + sum_{e in CSR row d} dinv[src]*dinv[d] * h[src]
// One wave per node; 64/(C/4) edges processed in parallel, shfl_xor combine.
template <int C>
__global__ __launch_bounds__(256) void aggregate_kernel(
    const float* __restrict__ h, const int* __restrict__ row_ptr,
    const int* __restrict__ csr_src, const float* __restrict__ dinv,
    float* __restrict__ out, int N)
{
    constexpr int TPN = C / 4;       // lanes per row slice: 32 (C=128) / 16 (C=64)
    constexpr int PAR = 64 / TPN;    // edges in flight per wave: 2 / 4
    int wid = (blockIdx.x * 256 + threadIdx.x) >> 6;
    if (wid >= N) return;
    int lane = threadIdx.x & 63;
    int part = lane / TPN;
    int c0 = (lane % TPN) * 4;
    float dd = dinv[wid];
    float4 acc = make_float4(0.f, 0.f, 0.f, 0.f);
    int e1 = row_ptr[wid + 1];
    for (int e = row_ptr[wid] + part; e < e1; e += PAR) {
        int s = csr_src[e];
        float w = dinv[s] * dd;
        float4 v = *(const float4*)&h[(size_t)s * C + c0];
        acc.x = fmaf(v.x, w, acc.x);
        acc.y = fmaf(v.y, w, acc.y);
        acc.z = fmaf(v.z, w, acc.z);
        acc.w = fmaf(v.w, w, acc.w);
    }
    #pragma unroll
    for (int off = TPN; off < 64; off <<= 1) {
        acc.x += __shfl_xor(acc.x, off, 64);
        acc.y += __shfl_xor(acc.y, off, 64);
        acc.z += __shfl_xor(acc.z, off, 64);
        acc.w += __shfl_xor(acc.w, off, 64);
    }
    if (part == 0) {
        float4 sv = *(const float4*)&h[(size_t)wid * C + c0];
        float w2 = dd * dd;
        acc.x = fmaf(sv.x, w2, acc.x);
        acc.y = fmaf(sv.y, w2, acc.y);
        acc.z = fmaf(sv.z, w2, acc.z);
        acc.w = fmaf(sv.w, w2, acc.w);
        *(float4*)&out[(size_t)wid * C + c0] = acc;
    }
}

// Per-channel sum & sumsq over rows -> sums[0..C) = sum, sums[C..2C) = sumsq
template <int C>
__global__ __launch_bounds__(256) void stats_kernel(const float* __restrict__ h,
                                                    float* __restrict__ sums, int N)
{
    constexpr int CG = C / 4;
    constexpr int RPB = 256 / CG;
    __shared__ float red[RPB][CG][8];
    int tid = threadIdx.x;
    int cg = tid % CG, rg = tid / CG;
    int c0 = cg * 4;
    float4 s = make_float4(0.f, 0.f, 0.f, 0.f);
    float4 q = make_float4(0.f, 0.f, 0.f, 0.f);
    for (int r = blockIdx.x * RPB + rg; r < N; r += gridDim.x * RPB) {
        float4 v = *(const float4*)&h[(size_t)r * C + c0];
        s.x += v.x; s.y += v.y; s.z += v.z; s.w += v.w;
        q.x = fmaf(v.x, v.x, q.x); q.y = fmaf(v.y, v.y, q.y);
        q.z = fmaf(v.z, v.z, q.z); q.w = fmaf(v.w, v.w, q.w);
    }
    float* rr = red[rg][cg];
    rr[0] = s.x; rr[1] = s.y; rr[2] = s.z; rr[3] = s.w;
    rr[4] = q.x; rr[5] = q.y; rr[6] = q.z; rr[7] = q.w;
    __syncthreads();
    if (rg == 0) {
        float a[8];
        #pragma unroll
        for (int i = 0; i < 8; ++i) a[i] = red[0][cg][i];
        for (int r2 = 1; r2 < RPB; ++r2)
            #pragma unroll
            for (int i = 0; i < 8; ++i) a[i] += red[r2][cg][i];
        atomicAdd(&sums[c0 + 0], a[0]); atomicAdd(&sums[c0 + 1], a[1]);
        atomicAdd(&sums[c0 + 2], a[2]); atomicAdd(&sums[c0 + 3], a[3]);
        atomicAdd(&sums[C + c0 + 0], a[4]); atomicAdd(&sums[C + c0 + 1], a[5]);
        atomicAdd(&sums[C + c0 + 2], a[6]); atomicAdd(&sums[C + c0 + 3], a[7]);
    }
}

template <int C, bool RELU>
__global__ void bn_apply_kernel(const float* __restrict__ in, float* __restrict__ out,
                                const float* __restrict__ sums, const float* __restrict__ gamma,
                                const float* __restrict__ beta, int N)
{
    int total = N * (C / 4);
    int i = blockIdx.x * blockDim.x + threadIdx.x;
    int stride = gridDim.x * blockDim.x;
    float invN = 1.0f / (float)N;
    for (; i < total; i += stride) {
        int c0 = (i * 4) % C;
        float4 v = *(const float4*)&in[(size_t)i * 4];
        float4 sm = *(const float4*)&sums[c0];
        float4 sq = *(const float4*)&sums[C + c0];
        float4 g = *(const float4*)&gamma[c0];
        float4 b = *(const float4*)&beta[c0];
        float mu, var, scl;
        mu = sm.x * invN; var = sq.x * invN - mu * mu; scl = rsqrtf(var + BN_EPS) * g.x;
        v.x = fmaf(v.x - mu, scl, b.x);
        mu = sm.y * invN; var = sq.y * invN - mu * mu; scl = rsqrtf(var + BN_EPS) * g.y;
        v.y = fmaf(v.y - mu, scl, b.y);
        mu = sm.z * invN; var = sq.z * invN - mu * mu; scl = rsqrtf(var + BN_EPS) * g.z;
        v.z = fmaf(v.z - mu, scl, b.z);
        mu = sm.w * invN; var = sq.w * invN - mu * mu; scl = rsqrtf(var + BN_EPS) * g.w;
        v.w = fmaf(v.w - mu, scl, b.w);
        if (RELU) {
            v.x = fmaxf(v.x, 0.f); v.y = fmaxf(v.y, 0.f);
            v.z = fmaxf(v.z, 0.f); v.w = fmaxf(v.w, 0.f);
        }
        *(float4*)&out[(size_t)i * 4] = v;
    }
}

extern "C" void kernel_launch(void* const* d_in, const int* in_sizes, int n_in,
                              void* d_out, int out_size, void* d_ws, size_t ws_size,
                              hipStream_t stream) {
    const float* x      = (const float*)d_in[0];
    const int*   ei     = (const int*)d_in[1];
    const float* W1     = (const float*)d_in[2];
    // d_in[3] = b1: cancels in BN1 (mean subtraction) -> skipped
    const float* gamma1 = (const float*)d_in[4];
    const float* beta1  = (const float*)d_in[5];
    const float* W2     = (const float*)d_in[6];
    // d_in[7] = b2: cancels in BN2 -> skipped
    const float* gamma2 = (const float*)d_in[8];
    const float* beta2  = (const float*)d_in[9];

    const int N = in_sizes[0] / IN_C;   // 100000
    const int E = in_sizes[1] / 2;      // 1600000
    const int* src = ei;
    const int* dst = ei + E;

    // ws layout (4B words):
    //  [0,384)        stats1(256) + stats2(128)
    //  [384, +N)      dinv (f32)
    //  [.., +N)       deg (int) -- reused as cursor after scan
    //  [.., +N+16)    row_ptr (int)
    //  [.., +256)     tilesums (int)
    //  [.., +E)       csr_src (int)
    //  bufA: N*128 f32 ; bufB: N*128 f32
    float* ws     = (float*)d_ws;
    float* stats1 = ws;
    float* stats2 = ws + 256;
    float* dinv   = ws + 384;
    int*   deg    = (int*)(dinv + N);
    int*   cursor = deg;                 // alias: deg dead after scan
    int*   row_ptr = deg + N;
    int*   tilesums = row_ptr + N + 16;
    int*   csr_src = tilesums + 256;     // word offset 384+3N+272 (16-aligned for N%16==0)
    float* bufA   = (float*)(csr_src + E);
    float* bufB   = bufA + (size_t)N * HID_C;
    float* h2     = bufA;                       // layer2 reuses bufA (N*64)
    float* agg2   = bufA + (size_t)N * OUT_C2;  // second half of bufA

    const int numTiles = (N + 1023) / 1024;

    zero_f_kernel<<<2, 256, 0, stream>>>(ws, 384);
    zero_i_kernel<<<(N + 255) / 256, 256, 0, stream>>>(deg, N);
    degree_kernel<<<2048, 256, 0, stream>>>(dst, deg, E);
    dinv_kernel<<<(N + 255) / 256, 256, 0, stream>>>(deg, dinv, N);
    scan1_kernel<<<numTiles, 256, 0, stream>>>(deg, row_ptr, tilesums, N);
    scan2_kernel<<<1, 256, 0, stream>>>(tilesums, numTiles);
    scan3_kernel<<<(N + 255) / 256, 256, 0, stream>>>(row_ptr, cursor, tilesums, N, E);
    csr_build_kernel<<<2048, 256, 0, stream>>>(src, dst, cursor, csr_src, E);

    // Layer 1: h1 = x@W1 (bufA); bufB = aggregate(h1)
    gemm_kernel<HID_C, false><<<(N + 31) / 32, 256, 0, stream>>>(
        x, W1, bufA, nullptr, nullptr, nullptr, N);
    aggregate_kernel<HID_C><<<(N + 3) / 4, 256, 0, stream>>>(
        bufA, row_ptr, csr_src, dinv, bufB, N);
    stats_kernel<HID_C><<<256, 256, 0, stream>>>(bufB, stats1, N);

    // Layer 2: h2 = relu(bn1(bufB)) @ W2 (BN fused in load); agg2 = aggregate(h2)
    gemm_kernel<OUT_C2, true><<<(N + 63) / 64, 256, 0, stream>>>(
        bufB, W2, h2, stats1, gamma1, beta1, N);
    aggregate_kernel<OUT_C2><<<(N + 3) / 4, 256, 0, stream>>>(
        h2, row_ptr, csr_src, dinv, agg2, N);
    stats_kernel<OUT_C2><<<256, 256, 0, stream>>>(agg2, stats2, N);

    // BN2 -> d_out
    bn_apply_kernel<OUT_C2, false><<<2048, 256, 0, stream>>>(
        agg2, (float*)d_out, stats2, gamma2, beta2, N);
}

// Round 3
// 505.783 us; speedup vs baseline: 8.3114x; 1.1772x over previous
//
#include <hip/hip_runtime.h>
#include <hip/hip_bf16.h>

// GNN decoder: 2x (GCNConv -> BatchNorm[-> ReLU]) on N=100000 nodes, E=1.6M edges.
// Round 3: bf16 intermediate buffers (halves gather traffic in the dominant
// aggregate kernels) + MFMA bf16 GEMMs with fragment-ordered W (no LDS).
// CSR-by-dst gather aggregation (round 2). Bias cancels in BN -> b1/b2 skipped.
// BN1+ReLU fused into GEMM2 A-operand load. BN scale/shift precomputed.

#define IN_C 128
#define HID_C 128
#define OUT_C2 64
#define BN_EPS 1e-5f

typedef __attribute__((ext_vector_type(8))) short short8v;
typedef __attribute__((ext_vector_type(4))) float float4v;

__device__ inline ushort f2bf(float f) {
    union { float f; unsigned u; } x; x.f = f;
    return (ushort)((x.u + 0x7fffu + ((x.u >> 16) & 1u)) >> 16);  // RNE
}
__device__ inline float bf2f(ushort u) {
    union { unsigned u; float f; } x; x.u = ((unsigned)u) << 16;
    return x.f;
}

__global__ void zero_f_kernel(float* __restrict__ p, int n) {
    int i = blockIdx.x * blockDim.x + threadIdx.x;
    if (i < n) p[i] = 0.0f;
}

__global__ void zero_i_kernel(int* __restrict__ p, int n) {
    int i = blockIdx.x * blockDim.x + threadIdx.x;
    if (i < n) p[i] = 0;
}

__global__ void degree_kernel(const int* __restrict__ dst, int* __restrict__ deg, int E) {
    int i = blockIdx.x * blockDim.x + threadIdx.x;
    int stride = gridDim.x * blockDim.x;
    for (; i < E; i += stride)
        atomicAdd(&deg[dst[i]], 1);
}

__global__ void dinv_kernel(const int* __restrict__ deg, float* __restrict__ dinv, int N) {
    int i = blockIdx.x * blockDim.x + threadIdx.x;
    if (i < N) dinv[i] = rsqrtf((float)deg[i] + 1.0f);  // +1 self-loop; always > 0
}

// ---- exclusive scan of deg[N] -> row_ptr[N] (+ tile sums), 1024-elem tiles ----
__global__ __launch_bounds__(256) void scan1_kernel(const int* __restrict__ in,
                                                    int* __restrict__ out,
                                                    int* __restrict__ tilesums, int n)
{
    __shared__ int sdata[256];
    int t = threadIdx.x;
    int idx = blockIdx.x * 1024 + t * 4;
    int4 v = make_int4(0, 0, 0, 0);
    if (idx + 3 < n) v = *(const int4*)&in[idx];
    else {
        if (idx < n)     v.x = in[idx];
        if (idx + 1 < n) v.y = in[idx + 1];
        if (idx + 2 < n) v.z = in[idx + 2];
        if (idx + 3 < n) v.w = in[idx + 3];
    }
    int s1 = v.x, s2 = s1 + v.y, s3 = s2 + v.z, s4 = s3 + v.w;
    sdata[t] = s4;
    __syncthreads();
    for (int off = 1; off < 256; off <<= 1) {
        int val = (t >= off) ? sdata[t - off] : 0;
        __syncthreads();
        sdata[t] += val;
        __syncthreads();
    }
    int prev = sdata[t] - s4;
    if (idx < n)     out[idx]     = prev;
    if (idx + 1 < n) out[idx + 1] = prev + s1;
    if (idx + 2 < n) out[idx + 2] = prev + s2;
    if (idx + 3 < n) out[idx + 3] = prev + s3;
    if (t == 255) tilesums[blockIdx.x] = sdata[255];
}

__global__ void scan2_kernel(int* __restrict__ ts, int nt) {
    __shared__ int sdata[256];
    int t = threadIdx.x;
    int v = (t < nt) ? ts[t] : 0;
    sdata[t] = v;
    __syncthreads();
    for (int off = 1; off < 256; off <<= 1) {
        int val = (t >= off) ? sdata[t - off] : 0;
        __syncthreads();
        sdata[t] += val;
        __syncthreads();
    }
    if (t < nt) ts[t] = sdata[t] - v;  // exclusive
}

__global__ void scan3_kernel(int* __restrict__ row_ptr, int* __restrict__ cursor,
                             const int* __restrict__ ts, int n, int total) {
    int i = blockIdx.x * blockDim.x + threadIdx.x;
    if (i == 0) row_ptr[n] = total;
    if (i < n) {
        int rp = row_ptr[i] + ts[i >> 10];
        row_ptr[i] = rp;
        cursor[i] = rp;
    }
}

__global__ void csr_build_kernel(const int* __restrict__ src, const int* __restrict__ dst,
                                 int* __restrict__ cursor, int* __restrict__ csr_src, int E) {
    int i = blockIdx.x * blockDim.x + threadIdx.x;
    int stride = gridDim.x * blockDim.x;
    for (; i < E; i += stride) {
        int pos = atomicAdd(&cursor[dst[i]], 1);
        csr_src[pos] = src[i];
    }
}

// W[128][OC] f32 -> fragment-ordered bf16: wfrag[kk][ct][lane][e],
// element = W[kk*32 + (lane>>4)*8 + e][ct*16 + (lane&15)]
template <int OC>
__global__ void wreorder_kernel(const float* __restrict__ W, ushort* __restrict__ wfrag) {
    constexpr int NCT = OC / 16;
    int t = blockIdx.x * 256 + threadIdx.x;
    if (t >= 4 * NCT * 64) return;
    int lane = t & 63;
    int rest = t >> 6;
    int ct = rest % NCT;
    int kk = rest / NCT;
    int col = ct * 16 + (lane & 15);
    int krow = kk * 32 + (lane >> 4) * 8;
    ushort tmp[8];
    #pragma unroll
    for (int e = 0; e < 8; ++e)
        tmp[e] = f2bf(W[(size_t)(krow + e) * OC + col]);
    uint4 st;
    st.x = (uint)tmp[0] | ((uint)tmp[1] << 16);
    st.y = (uint)tmp[2] | ((uint)tmp[3] << 16);
    st.z = (uint)tmp[4] | ((uint)tmp[5] << 16);
    st.w = (uint)tmp[6] | ((uint)tmp[7] << 16);
    *(uint4*)&wfrag[(size_t)t * 8] = st;
}

// Y[N][OC] bf16 = A @ W via mfma_f32_16x16x32_bf16. One wave per 16 rows, no LDS.
// A-frag: row = lane&15, k = kk*32 + (lane>>4)*8 + j (consecutive -> vector load).
// C/D: col = lane&15, row = (lane>>4)*4 + reg.
// BN_IN: A = relu(bf16_in * sc[k] + sh[k]) computed in f32, rounded to bf16.
template <int OC, bool BN_IN>
__global__ __launch_bounds__(256) void mfma_gemm_kernel(
    const void* __restrict__ Xv, const ushort* __restrict__ wfrag,
    ushort* __restrict__ Y, const float* __restrict__ sc,
    const float* __restrict__ sh, int N)
{
    constexpr int NCT = OC / 16;
    int wave = (blockIdx.x * 256 + threadIdx.x) >> 6;
    int lane = threadIdx.x & 63;
    int row16 = wave * 16;
    if (row16 >= N) return;
    int r = lane & 15;
    int g = lane >> 4;
    int row = row16 + r;  // N % 16 == 0 -> always < N

    float4v acc[NCT];
    #pragma unroll
    for (int ct = 0; ct < NCT; ++ct) acc[ct] = (float4v){0.f, 0.f, 0.f, 0.f};

    const short8v* wf = (const short8v*)wfrag;

    #pragma unroll
    for (int kk = 0; kk < 4; ++kk) {
        int k0 = kk * 32 + g * 8;
        short8v a;
        if constexpr (!BN_IN) {
            const float* xp = (const float*)Xv + (size_t)row * 128 + k0;
            float4 x0 = *(const float4*)xp;
            float4 x1 = *(const float4*)(xp + 4);
            a[0] = (short)f2bf(x0.x); a[1] = (short)f2bf(x0.y);
            a[2] = (short)f2bf(x0.z); a[3] = (short)f2bf(x0.w);
            a[4] = (short)f2bf(x1.x); a[5] = (short)f2bf(x1.y);
            a[6] = (short)f2bf(x1.z); a[7] = (short)f2bf(x1.w);
        } else {
            const ushort* xp = (const ushort*)Xv + (size_t)row * 128 + k0;
            uint4 v = *(const uint4*)xp;
            float4 s0 = *(const float4*)&sc[k0];
            float4 s1 = *(const float4*)&sc[k0 + 4];
            float4 h0 = *(const float4*)&sh[k0];
            float4 h1 = *(const float4*)&sh[k0 + 4];
            a[0] = (short)f2bf(fmaxf(fmaf(bf2f((ushort)(v.x & 0xffff)), s0.x, h0.x), 0.f));
            a[1] = (short)f2bf(fmaxf(fmaf(bf2f((ushort)(v.x >> 16)),    s0.y, h0.y), 0.f));
            a[2] = (short)f2bf(fmaxf(fmaf(bf2f((ushort)(v.y & 0xffff)), s0.z, h0.z), 0.f));
            a[3] = (short)f2bf(fmaxf(fmaf(bf2f((ushort)(v.y >> 16)),    s0.w, h0.w), 0.f));
            a[4] = (short)f2bf(fmaxf(fmaf(bf2f((ushort)(v.z & 0xffff)), s1.x, h1.x), 0.f));
            a[5] = (short)f2bf(fmaxf(fmaf(bf2f((ushort)(v.z >> 16)),    s1.y, h1.y), 0.f));
            a[6] = (short)f2bf(fmaxf(fmaf(bf2f((ushort)(v.w & 0xffff)), s1.z, h1.z), 0.f));
            a[7] = (short)f2bf(fmaxf(fmaf(bf2f((ushort)(v.w >> 16)),    s1.w, h1.w), 0.f));
        }
        #pragma unroll
        for (int ct = 0; ct < NCT; ++ct) {
            short8v b = wf[((size_t)(kk * NCT + ct)) * 64 + lane];
            acc[ct] = __builtin_amdgcn_mfma_f32_16x16x32_bf16(a, b, acc[ct], 0, 0, 0);
        }
    }
    #pragma unroll
    for (int ct = 0; ct < NCT; ++ct) {
        #pragma unroll
        for (int i = 0; i < 4; ++i) {
            int orow = row16 + g * 4 + i;
            Y[(size_t)orow * OC + ct * 16 + r] = f2bf(acc[ct][i]);
        }
    }
}

// out[d] = dinv[d]^2 * h[d] + sum_{e in CSR row d} dinv[src]*dinv[d] * h[src]
// h is bf16; one wave per node, PAR edges in flight, 8 channels (16 B) per lane.
template <int C, bool OUT_BF16>
__global__ __launch_bounds__(256) void aggregate_kernel(
    const ushort* __restrict__ h, const int* __restrict__ row_ptr,
    const int* __restrict__ csr_src, const float* __restrict__ dinv,
    void* __restrict__ outv, int N)
{
    constexpr int TPN = C / 8;     // 16 (C=128) / 8 (C=64)
    constexpr int PAR = 64 / TPN;  // 4 / 8
    int wid = (blockIdx.x * 256 + threadIdx.x) >> 6;
    if (wid >= N) return;
    int lane = threadIdx.x & 63;
    int part = lane / TPN;
    int c0 = (lane % TPN) * 8;
    float dd = dinv[wid];
    float acc[8] = {0.f, 0.f, 0.f, 0.f, 0.f, 0.f, 0.f, 0.f};
    int e1 = row_ptr[wid + 1];
    for (int e = row_ptr[wid] + part; e < e1; e += PAR) {
        int s = csr_src[e];
        float w = dinv[s] * dd;
        uint4 v = *(const uint4*)&h[(size_t)s * C + c0];
        acc[0] = fmaf(bf2f((ushort)(v.x & 0xffff)), w, acc[0]);
        acc[1] = fmaf(bf2f((ushort)(v.x >> 16)),    w, acc[1]);
        acc[2] = fmaf(bf2f((ushort)(v.y & 0xffff)), w, acc[2]);
        acc[3] = fmaf(bf2f((ushort)(v.y >> 16)),    w, acc[3]);
        acc[4] = fmaf(bf2f((ushort)(v.z & 0xffff)), w, acc[4]);
        acc[5] = fmaf(bf2f((ushort)(v.z >> 16)),    w, acc[5]);
        acc[6] = fmaf(bf2f((ushort)(v.w & 0xffff)), w, acc[6]);
        acc[7] = fmaf(bf2f((ushort)(v.w >> 16)),    w, acc[7]);
    }
    #pragma unroll
    for (int off = TPN; off < 64; off <<= 1) {
        #pragma unroll
        for (int j = 0; j < 8; ++j)
            acc[j] += __shfl_xor(acc[j], off, 64);
    }
    if (part == 0) {
        uint4 v = *(const uint4*)&h[(size_t)wid * C + c0];
        float w2 = dd * dd;
        acc[0] = fmaf(bf2f((ushort)(v.x & 0xffff)), w2, acc[0]);
        acc[1] = fmaf(bf2f((ushort)(v.x >> 16)),    w2, acc[1]);
        acc[2] = fmaf(bf2f((ushort)(v.y & 0xffff)), w2, acc[2]);
        acc[3] = fmaf(bf2f((ushort)(v.y >> 16)),    w2, acc[3]);
        acc[4] = fmaf(bf2f((ushort)(v.z & 0xffff)), w2, acc[4]);
        acc[5] = fmaf(bf2f((ushort)(v.z >> 16)),    w2, acc[5]);
        acc[6] = fmaf(bf2f((ushort)(v.w & 0xffff)), w2, acc[6]);
        acc[7] = fmaf(bf2f((ushort)(v.w >> 16)),    w2, acc[7]);
        if constexpr (OUT_BF16) {
            ushort* out = (ushort*)outv;
            uint4 st;
            st.x = (uint)f2bf(acc[0]) | ((uint)f2bf(acc[1]) << 16);
            st.y = (uint)f2bf(acc[2]) | ((uint)f2bf(acc[3]) << 16);
            st.z = (uint)f2bf(acc[4]) | ((uint)f2bf(acc[5]) << 16);
            st.w = (uint)f2bf(acc[6]) | ((uint)f2bf(acc[7]) << 16);
            *(uint4*)&out[(size_t)wid * C + c0] = st;
        } else {
            float* out = (float*)outv;
            *(float4*)&out[(size_t)wid * C + c0] =
                make_float4(acc[0], acc[1], acc[2], acc[3]);
            *(float4*)&out[(size_t)wid * C + c0 + 4] =
                make_float4(acc[4], acc[5], acc[6], acc[7]);
        }
    }
}

// Per-channel sum & sumsq over bf16 rows -> sums[0..C)=sum, sums[C..2C)=sumsq
template <int C>
__global__ __launch_bounds__(256) void stats_bf16_kernel(const ushort* __restrict__ h,
                                                         float* __restrict__ sums, int N)
{
    constexpr int CG = C / 8;      // 16
    constexpr int RPB = 256 / CG;  // 16
    __shared__ float red[RPB][CG][16];
    int tid = threadIdx.x;
    int cg = tid % CG, rg = tid / CG;
    int c0 = cg * 8;
    float s[8] = {0.f,0.f,0.f,0.f,0.f,0.f,0.f,0.f};
    float q[8] = {0.f,0.f,0.f,0.f,0.f,0.f,0.f,0.f};
    for (int r = blockIdx.x * RPB + rg; r < N; r += gridDim.x * RPB) {
        uint4 v = *(const uint4*)&h[(size_t)r * C + c0];
        float f0 = bf2f((ushort)(v.x & 0xffff)), f1 = bf2f((ushort)(v.x >> 16));
        float f2 = bf2f((ushort)(v.y & 0xffff)), f3 = bf2f((ushort)(v.y >> 16));
        float f4 = bf2f((ushort)(v.z & 0xffff)), f5 = bf2f((ushort)(v.z >> 16));
        float f6 = bf2f((ushort)(v.w & 0xffff)), f7 = bf2f((ushort)(v.w >> 16));
        s[0]+=f0; s[1]+=f1; s[2]+=f2; s[3]+=f3; s[4]+=f4; s[5]+=f5; s[6]+=f6; s[7]+=f7;
        q[0]=fmaf(f0,f0,q[0]); q[1]=fmaf(f1,f1,q[1]); q[2]=fmaf(f2,f2,q[2]); q[3]=fmaf(f3,f3,q[3]);
        q[4]=fmaf(f4,f4,q[4]); q[5]=fmaf(f5,f5,q[5]); q[6]=fmaf(f6,f6,q[6]); q[7]=fmaf(f7,f7,q[7]);
    }
    #pragma unroll
    for (int j = 0; j < 8; ++j) { red[rg][cg][j] = s[j]; red[rg][cg][8 + j] = q[j]; }
    __syncthreads();
    if (rg == 0) {
        float a[16];
        #pragma unroll
        for (int i = 0; i < 16; ++i) a[i] = red[0][cg][i];
        for (int r2 = 1; r2 < RPB; ++r2)
            #pragma unroll
            for (int i = 0; i < 16; ++i) a[i] += red[r2][cg][i];
        #pragma unroll
        for (int j = 0; j < 8; ++j) {
            atomicAdd(&sums[c0 + j], a[j]);
            atomicAdd(&sums[C + c0 + j], a[8 + j]);
        }
    }
}

// Per-channel sum & sumsq over f32 rows (for agg2)
template <int C>
__global__ __launch_bounds__(256) void stats_f32_kernel(const float* __restrict__ h,
                                                        float* __restrict__ sums, int N)
{
    constexpr int CG = C / 4;
    constexpr int RPB = 256 / CG;
    __shared__ float red[RPB][CG][8];
    int tid = threadIdx.x;
    int cg = tid % CG, rg = tid / CG;
    int c0 = cg * 4;
    float4 s = make_float4(0.f, 0.f, 0.f, 0.f);
    float4 q = make_float4(0.f, 0.f, 0.f, 0.f);
    for (int r = blockIdx.x * RPB + rg; r < N; r += gridDim.x * RPB) {
        float4 v = *(const float4*)&h[(size_t)r * C + c0];
        s.x += v.x; s.y += v.y; s.z += v.z; s.w += v.w;
        q.x = fmaf(v.x, v.x, q.x); q.y = fmaf(v.y, v.y, q.y);
        q.z = fmaf(v.z, v.z, q.z); q.w = fmaf(v.w, v.w, q.w);
    }
    float* rr = red[rg][cg];
    rr[0] = s.x; rr[1] = s.y; rr[2] = s.z; rr[3] = s.w;
    rr[4] = q.x; rr[5] = q.y; rr[6] = q.z; rr[7] = q.w;
    __syncthreads();
    if (rg == 0) {
        float a[8];
        #pragma unroll
        for (int i = 0; i < 8; ++i) a[i] = red[0][cg][i];
        for (int r2 = 1; r2 < RPB; ++r2)
            #pragma unroll
            for (int i = 0; i < 8; ++i) a[i] += red[r2][cg][i];
        #pragma unroll
        for (int j = 0; j < 4; ++j) {
            atomicAdd(&sums[c0 + j], a[j]);
            atomicAdd(&sums[C + c0 + j], a[4 + j]);
        }
    }
}

__global__ void bnprep_kernel(const float* __restrict__ stats, const float* __restrict__ gamma,
                              const float* __restrict__ beta, float* __restrict__ sc,
                              float* __restrict__ sh, int C, int N) {
    int c = threadIdx.x;
    if (c < C) {
        float invN = 1.0f / (float)N;
        float mu = stats[c] * invN;
        float var = stats[C + c] * invN - mu * mu;
        float s = rsqrtf(var + BN_EPS) * gamma[c];
        sc[c] = s;
        sh[c] = beta[c] - mu * s;
    }
}

template <int C>
__global__ void bn_apply_kernel(const float* __restrict__ in, float* __restrict__ out,
                                const float* __restrict__ sc, const float* __restrict__ sh,
                                int N)
{
    int total = N * (C / 4);
    int i = blockIdx.x * blockDim.x + threadIdx.x;
    int stride = gridDim.x * blockDim.x;
    for (; i < total; i += stride) {
        int c0 = (i * 4) % C;
        float4 v = *(const float4*)&in[(size_t)i * 4];
        float4 s = *(const float4*)&sc[c0];
        float4 h = *(const float4*)&sh[c0];
        v.x = fmaf(v.x, s.x, h.x);
        v.y = fmaf(v.y, s.y, h.y);
        v.z = fmaf(v.z, s.z, h.z);
        v.w = fmaf(v.w, s.w, h.w);
        *(float4*)&out[(size_t)i * 4] = v;
    }
}

extern "C" void kernel_launch(void* const* d_in, const int* in_sizes, int n_in,
                              void* d_out, int out_size, void* d_ws, size_t ws_size,
                              hipStream_t stream) {
    const float* x      = (const float*)d_in[0];
    const int*   ei     = (const int*)d_in[1];
    const float* W1     = (const float*)d_in[2];
    // d_in[3] = b1: cancels in BN1 -> skipped
    const float* gamma1 = (const float*)d_in[4];
    const float* beta1  = (const float*)d_in[5];
    const float* W2     = (const float*)d_in[6];
    // d_in[7] = b2: cancels in BN2 -> skipped
    const float* gamma2 = (const float*)d_in[8];
    const float* beta2  = (const float*)d_in[9];

    const int N = in_sizes[0] / IN_C;   // 100000 (divisible by 16)
    const int E = in_sizes[1] / 2;      // 1600000
    const int* src = ei;
    const int* dst = ei + E;

    // ws layout (4-byte words; every block 16B-aligned by construction):
    float* ws     = (float*)d_ws;
    float* stats1 = ws;                  // 256
    float* stats2 = ws + 256;            // 128
    float* sc1    = ws + 384;            // 128
    float* sh1    = ws + 512;            // 128
    float* sc2    = ws + 640;            // 128 (64 used)
    float* sh2    = ws + 768;            // 128 (64 used)
    float* dinv   = ws + 896;            // N
    int*   deg    = (int*)(dinv + N);    // N (aliased as cursor after scan)
    int*   cursor = deg;
    int*   row_ptr = deg + N;            // N+16
    int*   tilesums = row_ptr + N + 16;  // 256
    int*   csr_src = tilesums + 256;     // E
    ushort* wfrag1 = (ushort*)(csr_src + E);        // 4*8*64*8 = 16384 bf16
    ushort* wfrag2 = wfrag1 + 16384;                // 4*4*64*8 = 8192 bf16
    ushort* h1     = wfrag2 + 8192;                 // N*128 bf16
    ushort* bufB   = h1 + (size_t)N * HID_C;        // N*128 bf16
    ushort* h2     = bufB + (size_t)N * HID_C;      // N*64 bf16
    float*  agg2   = (float*)(h2 + (size_t)N * OUT_C2);  // N*64 f32

    const int numTiles = (N + 1023) / 1024;

    zero_f_kernel<<<2, 256, 0, stream>>>(ws, 384);
    zero_i_kernel<<<(N + 255) / 256, 256, 0, stream>>>(deg, N);
    degree_kernel<<<2048, 256, 0, stream>>>(dst, deg, E);
    dinv_kernel<<<(N + 255) / 256, 256, 0, stream>>>(deg, dinv, N);
    scan1_kernel<<<numTiles, 256, 0, stream>>>(deg, row_ptr, tilesums, N);
    scan2_kernel<<<1, 256, 0, stream>>>(tilesums, numTiles);
    scan3_kernel<<<(N + 255) / 256, 256, 0, stream>>>(row_ptr, cursor, tilesums, N, E);
    csr_build_kernel<<<2048, 256, 0, stream>>>(src, dst, cursor, csr_src, E);

    wreorder_kernel<HID_C><<<8, 256, 0, stream>>>(W1, wfrag1);
    wreorder_kernel<OUT_C2><<<4, 256, 0, stream>>>(W2, wfrag2);

    // Layer 1: h1 = bf16(x @ W1); bufB = aggregate(h1) (bf16)
    mfma_gemm_kernel<HID_C, false><<<(N / 16 + 3) / 4, 256, 0, stream>>>(
        x, wfrag1, h1, nullptr, nullptr, N);
    aggregate_kernel<HID_C, true><<<(N + 3) / 4, 256, 0, stream>>>(
        h1, row_ptr, csr_src, dinv, bufB, N);
    stats_bf16_kernel<HID_C><<<256, 256, 0, stream>>>(bufB, stats1, N);
    bnprep_kernel<<<1, 256, 0, stream>>>(stats1, gamma1, beta1, sc1, sh1, HID_C, N);

    // Layer 2: h2 = bf16(relu(bn1(bufB)) @ W2); agg2 = aggregate(h2) (f32)
    mfma_gemm_kernel<OUT_C2, true><<<(N / 16 + 3) / 4, 256, 0, stream>>>(
        bufB, wfrag2, h2, sc1, sh1, N);
    aggregate_kernel<OUT_C2, false><<<(N + 3) / 4, 256, 0, stream>>>(
        h2, row_ptr, csr_src, dinv, agg2, N);
    stats_f32_kernel<OUT_C2><<<256, 256, 0, stream>>>(agg2, stats2, N);
    bnprep_kernel<<<1, 256, 0, stream>>>(stats2, gamma2, beta2, sc2, sh2, OUT_C2, N);

    bn_apply_kernel<OUT_C2><<<2048, 256, 0, stream>>>(agg2, (float*)d_out, sc2, sh2, N);
}

// Round 4
// 434.928 us; speedup vs baseline: 9.6655x; 1.1629x over previous
//
#include <hip/hip_runtime.h>
#include <hip/hip_bf16.h>

// GNN decoder: 2x (GCNConv -> BatchNorm[-> ReLU]) on N=100000 nodes, E=1.6M edges.
// Round 4: XCD-affine grouped CSR build (dst-range = blockIdx%8 -> one XCD's L2
// owns each cursor/csr region; kills the 107MB partial-line write amplification).
// GEMM epilogues pre-scale rows by dinv -> aggregate inner loop is pure adds.
// bf16 intermediates + no-LDS MFMA GEMMs (round 3). CSR gather agg (round 2).

#define IN_C 128
#define HID_C 128
#define OUT_C2 64
#define BN_EPS 1e-5f
#define NGROUPS 8

typedef __attribute__((ext_vector_type(8))) short short8v;
typedef __attribute__((ext_vector_type(4))) float float4v;

__device__ inline ushort f2bf(float f) {
    union { float f; unsigned u; } x; x.f = f;
    return (ushort)((x.u + 0x7fffu + ((x.u >> 16) & 1u)) >> 16);  // RNE
}
__device__ inline float bf2f(ushort u) {
    union { unsigned u; float f; } x; x.u = ((unsigned)u) << 16;
    return x.f;
}

__global__ void zero_f_kernel(float* __restrict__ p, int n) {
    int i = blockIdx.x * blockDim.x + threadIdx.x;
    if (i < n) p[i] = 0.0f;
}

__global__ void zero_i_kernel(int* __restrict__ p, int n) {
    int i = blockIdx.x * blockDim.x + threadIdx.x;
    if (i < n) p[i] = 0;
}

// Grouped degree: group g = blockIdx%8 counts only dst in [g*gsz, (g+1)*gsz).
// All of group g's atomics land in a ~50KB window -> XCD-local L2.
__global__ __launch_bounds__(256) void degree_grouped_kernel(
    const int* __restrict__ dst, int* __restrict__ deg, int E, int gsz)
{
    int g = blockIdx.x & (NGROUPS - 1);
    int bi = blockIdx.x / NGROUPS;
    int bpg = gridDim.x / NGROUPS;
    int lo = g * gsz, hi = lo + gsz;
    for (int i = bi * 256 + threadIdx.x; i < E; i += bpg * 256) {
        int d = dst[i];
        if (d >= lo && d < hi) atomicAdd(&deg[d], 1);
    }
}

__global__ void dinv_kernel(const int* __restrict__ deg, float* __restrict__ dinv, int N) {
    int i = blockIdx.x * blockDim.x + threadIdx.x;
    if (i < N) dinv[i] = rsqrtf((float)deg[i] + 1.0f);  // +1 self-loop; always > 0
}

// ---- exclusive scan of deg[N] -> row_ptr[N] (+ tile sums), 1024-elem tiles ----
__global__ __launch_bounds__(256) void scan1_kernel(const int* __restrict__ in,
                                                    int* __restrict__ out,
                                                    int* __restrict__ tilesums, int n)
{
    __shared__ int sdata[256];
    int t = threadIdx.x;
    int idx = blockIdx.x * 1024 + t * 4;
    int4 v = make_int4(0, 0, 0, 0);
    if (idx + 3 < n) v = *(const int4*)&in[idx];
    else {
        if (idx < n)     v.x = in[idx];
        if (idx + 1 < n) v.y = in[idx + 1];
        if (idx + 2 < n) v.z = in[idx + 2];
        if (idx + 3 < n) v.w = in[idx + 3];
    }
    int s1 = v.x, s2 = s1 + v.y, s3 = s2 + v.z, s4 = s3 + v.w;
    sdata[t] = s4;
    __syncthreads();
    for (int off = 1; off < 256; off <<= 1) {
        int val = (t >= off) ? sdata[t - off] : 0;
        __syncthreads();
        sdata[t] += val;
        __syncthreads();
    }
    int prev = sdata[t] - s4;
    if (idx < n)     out[idx]     = prev;
    if (idx + 1 < n) out[idx + 1] = prev + s1;
    if (idx + 2 < n) out[idx + 2] = prev + s2;
    if (idx + 3 < n) out[idx + 3] = prev + s3;
    if (t == 255) tilesums[blockIdx.x] = sdata[255];
}

__global__ void scan2_kernel(int* __restrict__ ts, int nt) {
    __shared__ int sdata[256];
    int t = threadIdx.x;
    int v = (t < nt) ? ts[t] : 0;
    sdata[t] = v;
    __syncthreads();
    for (int off = 1; off < 256; off <<= 1) {
        int val = (t >= off) ? sdata[t - off] : 0;
        __syncthreads();
        sdata[t] += val;
        __syncthreads();
    }
    if (t < nt) ts[t] = sdata[t] - v;  // exclusive
}

__global__ void scan3_kernel(int* __restrict__ row_ptr, int* __restrict__ cursor,
                             const int* __restrict__ ts, int n, int total) {
    int i = blockIdx.x * blockDim.x + threadIdx.x;
    if (i == 0) row_ptr[n] = total;
    if (i < n) {
        int rp = row_ptr[i] + ts[i >> 10];
        row_ptr[i] = rp;
        cursor[i] = rp;
    }
}

// Grouped CSR placement: group g handles dst range [lo,hi); its cursor atomics
// and csr_src writes stay in one XCD's L2 (region ~0.8MB), writeback once.
__global__ __launch_bounds__(256) void csr_build_grouped_kernel(
    const int* __restrict__ src, const int* __restrict__ dst,
    int* __restrict__ cursor, int* __restrict__ csr_src, int E, int gsz)
{
    int g = blockIdx.x & (NGROUPS - 1);
    int bi = blockIdx.x / NGROUPS;
    int bpg = gridDim.x / NGROUPS;
    int lo = g * gsz, hi = lo + gsz;
    for (int i = bi * 256 + threadIdx.x; i < E; i += bpg * 256) {
        int d = dst[i];
        if (d >= lo && d < hi) {
            int pos = atomicAdd(&cursor[d], 1);
            csr_src[pos] = src[i];
        }
    }
}

// W[128][OC] f32 -> fragment-ordered bf16: wfrag[kk][ct][lane][e],
// element = W[kk*32 + (lane>>4)*8 + e][ct*16 + (lane&15)]
template <int OC>
__global__ void wreorder_kernel(const float* __restrict__ W, ushort* __restrict__ wfrag) {
    constexpr int NCT = OC / 16;
    int t = blockIdx.x * 256 + threadIdx.x;
    if (t >= 4 * NCT * 64) return;
    int lane = t & 63;
    int rest = t >> 6;
    int ct = rest % NCT;
    int kk = rest / NCT;
    int col = ct * 16 + (lane & 15);
    int krow = kk * 32 + (lane >> 4) * 8;
    ushort tmp[8];
    #pragma unroll
    for (int e = 0; e < 8; ++e)
        tmp[e] = f2bf(W[(size_t)(krow + e) * OC + col]);
    uint4 st;
    st.x = (uint)tmp[0] | ((uint)tmp[1] << 16);
    st.y = (uint)tmp[2] | ((uint)tmp[3] << 16);
    st.z = (uint)tmp[4] | ((uint)tmp[5] << 16);
    st.w = (uint)tmp[6] | ((uint)tmp[7] << 16);
    *(uint4*)&wfrag[(size_t)t * 8] = st;
}

// Y[N][OC] bf16 = dinv[row] * (A @ W) via mfma_f32_16x16x32_bf16. No LDS.
// A-frag: row = lane&15, k = kk*32 + (lane>>4)*8 + j. C/D: col=lane&15,
// row=(lane>>4)*4+reg. BN_IN: A = relu(bf16_in*sc[k]+sh[k]) in f32 -> bf16.
// Pre-scaling by dinv makes the aggregate inner loop weight-free.
template <int OC, bool BN_IN>
__global__ __launch_bounds__(256) void mfma_gemm_kernel(
    const void* __restrict__ Xv, const ushort* __restrict__ wfrag,
    ushort* __restrict__ Y, const float* __restrict__ dinv,
    const float* __restrict__ sc, const float* __restrict__ sh, int N)
{
    constexpr int NCT = OC / 16;
    int wave = (blockIdx.x * 256 + threadIdx.x) >> 6;
    int lane = threadIdx.x & 63;
    int row16 = wave * 16;
    if (row16 >= N) return;
    int r = lane & 15;
    int g = lane >> 4;
    int row = row16 + r;  // N % 16 == 0 -> always < N

    float4v acc[NCT];
    #pragma unroll
    for (int ct = 0; ct < NCT; ++ct) acc[ct] = (float4v){0.f, 0.f, 0.f, 0.f};

    const short8v* wf = (const short8v*)wfrag;

    #pragma unroll
    for (int kk = 0; kk < 4; ++kk) {
        int k0 = kk * 32 + g * 8;
        short8v a;
        if constexpr (!BN_IN) {
            const float* xp = (const float*)Xv + (size_t)row * 128 + k0;
            float4 x0 = *(const float4*)xp;
            float4 x1 = *(const float4*)(xp + 4);
            a[0] = (short)f2bf(x0.x); a[1] = (short)f2bf(x0.y);
            a[2] = (short)f2bf(x0.z); a[3] = (short)f2bf(x0.w);
            a[4] = (short)f2bf(x1.x); a[5] = (short)f2bf(x1.y);
            a[6] = (short)f2bf(x1.z); a[7] = (short)f2bf(x1.w);
        } else {
            const ushort* xp = (const ushort*)Xv + (size_t)row * 128 + k0;
            uint4 v = *(const uint4*)xp;
            float4 s0 = *(const float4*)&sc[k0];
            float4 s1 = *(const float4*)&sc[k0 + 4];
            float4 h0 = *(const float4*)&sh[k0];
            float4 h1 = *(const float4*)&sh[k0 + 4];
            a[0] = (short)f2bf(fmaxf(fmaf(bf2f((ushort)(v.x & 0xffff)), s0.x, h0.x), 0.f));
            a[1] = (short)f2bf(fmaxf(fmaf(bf2f((ushort)(v.x >> 16)),    s0.y, h0.y), 0.f));
            a[2] = (short)f2bf(fmaxf(fmaf(bf2f((ushort)(v.y & 0xffff)), s0.z, h0.z), 0.f));
            a[3] = (short)f2bf(fmaxf(fmaf(bf2f((ushort)(v.y >> 16)),    s0.w, h0.w), 0.f));
            a[4] = (short)f2bf(fmaxf(fmaf(bf2f((ushort)(v.z & 0xffff)), s1.x, h1.x), 0.f));
            a[5] = (short)f2bf(fmaxf(fmaf(bf2f((ushort)(v.z >> 16)),    s1.y, h1.y), 0.f));
            a[6] = (short)f2bf(fmaxf(fmaf(bf2f((ushort)(v.w & 0xffff)), s1.z, h1.z), 0.f));
            a[7] = (short)f2bf(fmaxf(fmaf(bf2f((ushort)(v.w >> 16)),    s1.w, h1.w), 0.f));
        }
        #pragma unroll
        for (int ct = 0; ct < NCT; ++ct) {
            short8v b = wf[((size_t)(kk * NCT + ct)) * 64 + lane];
            acc[ct] = __builtin_amdgcn_mfma_f32_16x16x32_bf16(a, b, acc[ct], 0, 0, 0);
        }
    }
    float di[4];
    #pragma unroll
    for (int i = 0; i < 4; ++i) di[i] = dinv[row16 + g * 4 + i];
    #pragma unroll
    for (int ct = 0; ct < NCT; ++ct) {
        #pragma unroll
        for (int i = 0; i < 4; ++i) {
            int orow = row16 + g * 4 + i;
            Y[(size_t)orow * OC + ct * 16 + r] = f2bf(acc[ct][i] * di[i]);
        }
    }
}

// h' rows are pre-scaled by dinv[src]. out[d] = dinv[d]*(sum_e h'[src_e] + h'[d]).
// One wave per node, PAR edges in flight, 8 channels (16 B) per lane.
template <int C, bool OUT_BF16>
__global__ __launch_bounds__(256) void aggregate_kernel(
    const ushort* __restrict__ h, const int* __restrict__ row_ptr,
    const int* __restrict__ csr_src, const float* __restrict__ dinv,
    void* __restrict__ outv, int N)
{
    constexpr int TPN = C / 8;     // 16 (C=128) / 8 (C=64)
    constexpr int PAR = 64 / TPN;  // 4 / 8
    int wid = (blockIdx.x * 256 + threadIdx.x) >> 6;
    if (wid >= N) return;
    int lane = threadIdx.x & 63;
    int part = lane / TPN;
    int c0 = (lane % TPN) * 8;
    float acc[8] = {0.f, 0.f, 0.f, 0.f, 0.f, 0.f, 0.f, 0.f};
    int e1 = row_ptr[wid + 1];
    for (int e = row_ptr[wid] + part; e < e1; e += PAR) {
        int s = csr_src[e];
        uint4 v = *(const uint4*)&h[(size_t)s * C + c0];
        acc[0] += bf2f((ushort)(v.x & 0xffff));
        acc[1] += bf2f((ushort)(v.x >> 16));
        acc[2] += bf2f((ushort)(v.y & 0xffff));
        acc[3] += bf2f((ushort)(v.y >> 16));
        acc[4] += bf2f((ushort)(v.z & 0xffff));
        acc[5] += bf2f((ushort)(v.z >> 16));
        acc[6] += bf2f((ushort)(v.w & 0xffff));
        acc[7] += bf2f((ushort)(v.w >> 16));
    }
    #pragma unroll
    for (int off = TPN; off < 64; off <<= 1) {
        #pragma unroll
        for (int j = 0; j < 8; ++j)
            acc[j] += __shfl_xor(acc[j], off, 64);
    }
    if (part == 0) {
        uint4 v = *(const uint4*)&h[(size_t)wid * C + c0];
        acc[0] += bf2f((ushort)(v.x & 0xffff));
        acc[1] += bf2f((ushort)(v.x >> 16));
        acc[2] += bf2f((ushort)(v.y & 0xffff));
        acc[3] += bf2f((ushort)(v.y >> 16));
        acc[4] += bf2f((ushort)(v.z & 0xffff));
        acc[5] += bf2f((ushort)(v.z >> 16));
        acc[6] += bf2f((ushort)(v.w & 0xffff));
        acc[7] += bf2f((ushort)(v.w >> 16));
        float dd = dinv[wid];
        #pragma unroll
        for (int j = 0; j < 8; ++j) acc[j] *= dd;
        if constexpr (OUT_BF16) {
            ushort* out = (ushort*)outv;
            uint4 st;
            st.x = (uint)f2bf(acc[0]) | ((uint)f2bf(acc[1]) << 16);
            st.y = (uint)f2bf(acc[2]) | ((uint)f2bf(acc[3]) << 16);
            st.z = (uint)f2bf(acc[4]) | ((uint)f2bf(acc[5]) << 16);
            st.w = (uint)f2bf(acc[6]) | ((uint)f2bf(acc[7]) << 16);
            *(uint4*)&out[(size_t)wid * C + c0] = st;
        } else {
            float* out = (float*)outv;
            *(float4*)&out[(size_t)wid * C + c0] =
                make_float4(acc[0], acc[1], acc[2], acc[3]);
            *(float4*)&out[(size_t)wid * C + c0 + 4] =
                make_float4(acc[4], acc[5], acc[6], acc[7]);
        }
    }
}

// Per-channel sum & sumsq over bf16 rows -> sums[0..C)=sum, sums[C..2C)=sumsq
template <int C>
__global__ __launch_bounds__(256) void stats_bf16_kernel(const ushort* __restrict__ h,
                                                         float* __restrict__ sums, int N)
{
    constexpr int CG = C / 8;
    constexpr int RPB = 256 / CG;
    __shared__ float red[RPB][CG][16];
    int tid = threadIdx.x;
    int cg = tid % CG, rg = tid / CG;
    int c0 = cg * 8;
    float s[8] = {0.f,0.f,0.f,0.f,0.f,0.f,0.f,0.f};
    float q[8] = {0.f,0.f,0.f,0.f,0.f,0.f,0.f,0.f};
    for (int r = blockIdx.x * RPB + rg; r < N; r += gridDim.x * RPB) {
        uint4 v = *(const uint4*)&h[(size_t)r * C + c0];
        float f0 = bf2f((ushort)(v.x & 0xffff)), f1 = bf2f((ushort)(v.x >> 16));
        float f2 = bf2f((ushort)(v.y & 0xffff)), f3 = bf2f((ushort)(v.y >> 16));
        float f4 = bf2f((ushort)(v.z & 0xffff)), f5 = bf2f((ushort)(v.z >> 16));
        float f6 = bf2f((ushort)(v.w & 0xffff)), f7 = bf2f((ushort)(v.w >> 16));
        s[0]+=f0; s[1]+=f1; s[2]+=f2; s[3]+=f3; s[4]+=f4; s[5]+=f5; s[6]+=f6; s[7]+=f7;
        q[0]=fmaf(f0,f0,q[0]); q[1]=fmaf(f1,f1,q[1]); q[2]=fmaf(f2,f2,q[2]); q[3]=fmaf(f3,f3,q[3]);
        q[4]=fmaf(f4,f4,q[4]); q[5]=fmaf(f5,f5,q[5]); q[6]=fmaf(f6,f6,q[6]); q[7]=fmaf(f7,f7,q[7]);
    }
    #pragma unroll
    for (int j = 0; j < 8; ++j) { red[rg][cg][j] = s[j]; red[rg][cg][8 + j] = q[j]; }
    __syncthreads();
    if (rg == 0) {
        float a[16];
        #pragma unroll
        for (int i = 0; i < 16; ++i) a[i] = red[0][cg][i];
        for (int r2 = 1; r2 < RPB; ++r2)
            #pragma unroll
            for (int i = 0; i < 16; ++i) a[i] += red[r2][cg][i];
        #pragma unroll
        for (int j = 0; j < 8; ++j) {
            atomicAdd(&sums[c0 + j], a[j]);
            atomicAdd(&sums[C + c0 + j], a[8 + j]);
        }
    }
}

// Per-channel sum & sumsq over f32 rows (for agg2)
template <int C>
__global__ __launch_bounds__(256) void stats_f32_kernel(const float* __restrict__ h,
                                                        float* __restrict__ sums, int N)
{
    constexpr int CG = C / 4;
    constexpr int RPB = 256 / CG;
    __shared__ float red[RPB][CG][8];
    int tid = threadIdx.x;
    int cg = tid % CG, rg = tid / CG;
    int c0 = cg * 4;
    float4 s = make_float4(0.f, 0.f, 0.f, 0.f);
    float4 q = make_float4(0.f, 0.f, 0.f, 0.f);
    for (int r = blockIdx.x * RPB + rg; r < N; r += gridDim.x * RPB) {
        float4 v = *(const float4*)&h[(size_t)r * C + c0];
        s.x += v.x; s.y += v.y; s.z += v.z; s.w += v.w;
        q.x = fmaf(v.x, v.x, q.x); q.y = fmaf(v.y, v.y, q.y);
        q.z = fmaf(v.z, v.z, q.z); q.w = fmaf(v.w, v.w, q.w);
    }
    float* rr = red[rg][cg];
    rr[0] = s.x; rr[1] = s.y; rr[2] = s.z; rr[3] = s.w;
    rr[4] = q.x; rr[5] = q.y; rr[6] = q.z; rr[7] = q.w;
    __syncthreads();
    if (rg == 0) {
        float a[8];
        #pragma unroll
        for (int i = 0; i < 8; ++i) a[i] = red[0][cg][i];
        for (int r2 = 1; r2 < RPB; ++r2)
            #pragma unroll
            for (int i = 0; i < 8; ++i) a[i] += red[r2][cg][i];
        #pragma unroll
        for (int j = 0; j < 4; ++j) {
            atomicAdd(&sums[c0 + j], a[j]);
            atomicAdd(&sums[C + c0 + j], a[4 + j]);
        }
    }
}

__global__ void bnprep_kernel(const float* __restrict__ stats, const float* __restrict__ gamma,
                              const float* __restrict__ beta, float* __restrict__ sc,
                              float* __restrict__ sh, int C, int N) {
    int c = threadIdx.x;
    if (c < C) {
        float invN = 1.0f / (float)N;
        float mu = stats[c] * invN;
        float var = stats[C + c] * invN - mu * mu;
        float s = rsqrtf(var + BN_EPS) * gamma[c];
        sc[c] = s;
        sh[c] = beta[c] - mu * s;
    }
}

template <int C>
__global__ void bn_apply_kernel(const float* __restrict__ in, float* __restrict__ out,
                                const float* __restrict__ sc, const float* __restrict__ sh,
                                int N)
{
    int total = N * (C / 4);
    int i = blockIdx.x * blockDim.x + threadIdx.x;
    int stride = gridDim.x * blockDim.x;
    for (; i < total; i += stride) {
        int c0 = (i * 4) % C;
        float4 v = *(const float4*)&in[(size_t)i * 4];
        float4 s = *(const float4*)&sc[c0];
        float4 h = *(const float4*)&sh[c0];
        v.x = fmaf(v.x, s.x, h.x);
        v.y = fmaf(v.y, s.y, h.y);
        v.z = fmaf(v.z, s.z, h.z);
        v.w = fmaf(v.w, s.w, h.w);
        *(float4*)&out[(size_t)i * 4] = v;
    }
}

extern "C" void kernel_launch(void* const* d_in, const int* in_sizes, int n_in,
                              void* d_out, int out_size, void* d_ws, size_t ws_size,
                              hipStream_t stream) {
    const float* x      = (const float*)d_in[0];
    const int*   ei     = (const int*)d_in[1];
    const float* W1     = (const float*)d_in[2];
    // d_in[3] = b1: cancels in BN1 -> skipped
    const float* gamma1 = (const float*)d_in[4];
    const float* beta1  = (const float*)d_in[5];
    const float* W2     = (const float*)d_in[6];
    // d_in[7] = b2: cancels in BN2 -> skipped
    const float* gamma2 = (const float*)d_in[8];
    const float* beta2  = (const float*)d_in[9];

    const int N = in_sizes[0] / IN_C;   // 100000 (divisible by 16)
    const int E = in_sizes[1] / 2;      // 1600000
    const int* src = ei;
    const int* dst = ei + E;
    const int gsz = (N + NGROUPS - 1) / NGROUPS;  // 12500

    float* ws     = (float*)d_ws;
    float* stats1 = ws;                  // 256
    float* stats2 = ws + 256;            // 128
    float* sc1    = ws + 384;            // 128
    float* sh1    = ws + 512;            // 128
    float* sc2    = ws + 640;            // 128 (64 used)
    float* sh2    = ws + 768;            // 128 (64 used)
    float* dinv   = ws + 896;            // N
    int*   deg    = (int*)(dinv + N);    // N (aliased as cursor after scan)
    int*   cursor = deg;
    int*   row_ptr = deg + N;            // N+16
    int*   tilesums = row_ptr + N + 16;  // 256
    int*   csr_src = tilesums + 256;     // E
    ushort* wfrag1 = (ushort*)(csr_src + E);        // 16384 bf16
    ushort* wfrag2 = wfrag1 + 16384;                // 8192 bf16
    ushort* h1     = wfrag2 + 8192;                 // N*128 bf16 (pre-scaled by dinv)
    ushort* bufB   = h1 + (size_t)N * HID_C;        // N*128 bf16
    ushort* h2     = bufB + (size_t)N * HID_C;      // N*64 bf16 (pre-scaled by dinv)
    float*  agg2   = (float*)(h2 + (size_t)N * OUT_C2);  // N*64 f32

    const int numTiles = (N + 1023) / 1024;

    zero_f_kernel<<<2, 256, 0, stream>>>(ws, 384);
    zero_i_kernel<<<(N + 255) / 256, 256, 0, stream>>>(deg, N);
    degree_grouped_kernel<<<2048, 256, 0, stream>>>(dst, deg, E, gsz);
    dinv_kernel<<<(N + 255) / 256, 256, 0, stream>>>(deg, dinv, N);
    scan1_kernel<<<numTiles, 256, 0, stream>>>(deg, row_ptr, tilesums, N);
    scan2_kernel<<<1, 256, 0, stream>>>(tilesums, numTiles);
    scan3_kernel<<<(N + 255) / 256, 256, 0, stream>>>(row_ptr, cursor, tilesums, N, E);
    csr_build_grouped_kernel<<<2048, 256, 0, stream>>>(src, dst, cursor, csr_src, E, gsz);

    wreorder_kernel<HID_C><<<8, 256, 0, stream>>>(W1, wfrag1);
    wreorder_kernel<OUT_C2><<<4, 256, 0, stream>>>(W2, wfrag2);

    // Layer 1: h1 = bf16(dinv * (x @ W1)); bufB = aggregate(h1) (bf16)
    mfma_gemm_kernel<HID_C, false><<<(N / 16 + 3) / 4, 256, 0, stream>>>(
        x, wfrag1, h1, dinv, nullptr, nullptr, N);
    aggregate_kernel<HID_C, true><<<(N + 3) / 4, 256, 0, stream>>>(
        h1, row_ptr, csr_src, dinv, bufB, N);
    stats_bf16_kernel<HID_C><<<256, 256, 0, stream>>>(bufB, stats1, N);
    bnprep_kernel<<<1, 256, 0, stream>>>(stats1, gamma1, beta1, sc1, sh1, HID_C, N);

    // Layer 2: h2 = bf16(dinv * (relu(bn1(bufB)) @ W2)); agg2 = aggregate(h2) (f32)
    mfma_gemm_kernel<OUT_C2, true><<<(N / 16 + 3) / 4, 256, 0, stream>>>(
        bufB, wfrag2, h2, dinv, sc1, sh1, N);
    aggregate_kernel<OUT_C2, false><<<(N + 3) / 4, 256, 0, stream>>>(
        h2, row_ptr, csr_src, dinv, agg2, N);
    stats_f32_kernel<OUT_C2><<<256, 256, 0, stream>>>(agg2, stats2, N);
    bnprep_kernel<<<1, 256, 0, stream>>>(stats2, gamma2, beta2, sc2, sh2, OUT_C2, N);

    bn_apply_kernel<OUT_C2><<<2048, 256, 0, stream>>>(agg2, (float*)d_out, sc2, sh2, N);
}

// Round 5
// 430.122 us; speedup vs baseline: 9.7735x; 1.0112x over previous
//
#include <hip/hip_runtime.h>
#include <hip/hip_bf16.h>

// GNN decoder: 2x (GCNConv -> BatchNorm[-> ReLU]) on N=100000 nodes, E=1.6M edges.
// Round 5: aggregate gather loop 2x-unrolled (double MLP: two independent 1KB
// row-gathers in flight per wave-iteration; self-row load hoisted). degree/csr
// preprocessing switched to coalesced int4 streaming reads (was scattered 4B).
// dinv fused into scan1; zero kernels merged. Carries: XCD-affine CSR build
// (r4), dinv pre-scaled GEMM epilogues (r4), bf16 intermediates + no-LDS MFMA
// GEMMs (r3), CSR gather aggregation (r2), BN bias cancellation (r1).

#define IN_C 128
#define HID_C 128
#define OUT_C2 64
#define BN_EPS 1e-5f
#define NGROUPS 8

typedef __attribute__((ext_vector_type(8))) short short8v;
typedef __attribute__((ext_vector_type(4))) float float4v;

__device__ inline ushort f2bf(float f) {
    union { float f; unsigned u; } x; x.f = f;
    return (ushort)((x.u + 0x7fffu + ((x.u >> 16) & 1u)) >> 16);  // RNE
}
__device__ inline float bf2f(ushort u) {
    union { unsigned u; float f; } x; x.u = ((unsigned)u) << 16;
    return x.f;
}

// zero stats (384 f32) + deg (N int) in one launch
__global__ void init_kernel(float* __restrict__ stats, int* __restrict__ deg, int N) {
    int i = blockIdx.x * blockDim.x + threadIdx.x;
    if (i < 384) stats[i] = 0.0f;
    if (i < N) deg[i] = 0;
}

// Grouped degree histogram: group g = blockIdx%8 counts dst in [g*gsz,(g+1)*gsz).
// Coalesced int4 streaming reads; atomics land in a ~50KB XCD-local L2 window.
__global__ __launch_bounds__(256) void degree_grouped_kernel(
    const int* __restrict__ dst, int* __restrict__ deg, int E, int gsz)
{
    int g = blockIdx.x & (NGROUPS - 1);
    int bi = blockIdx.x / NGROUPS;
    int bpg = gridDim.x / NGROUPS;
    int lo = g * gsz, hi = lo + gsz;
    int E4 = E & ~3;
    int stride = bpg * 256 * 4;
    for (int i = (bi * 256 + threadIdx.x) * 4; i < E4; i += stride) {
        int4 d = *(const int4*)&dst[i];
        if (d.x >= lo && d.x < hi) atomicAdd(&deg[d.x], 1);
        if (d.y >= lo && d.y < hi) atomicAdd(&deg[d.y], 1);
        if (d.z >= lo && d.z < hi) atomicAdd(&deg[d.z], 1);
        if (d.w >= lo && d.w < hi) atomicAdd(&deg[d.w], 1);
    }
    if (bi == 0 && threadIdx.x < (E & 3)) {
        int d = dst[E4 + threadIdx.x];
        if (d >= lo && d < hi) atomicAdd(&deg[d], 1);
    }
}

// ---- exclusive scan of deg[N] -> row_ptr[N] (+ tile sums); also emits dinv ----
__global__ __launch_bounds__(256) void scan1_kernel(const int* __restrict__ in,
                                                    int* __restrict__ out,
                                                    int* __restrict__ tilesums,
                                                    float* __restrict__ dinv, int n)
{
    __shared__ int sdata[256];
    int t = threadIdx.x;
    int idx = blockIdx.x * 1024 + t * 4;
    int4 v = make_int4(0, 0, 0, 0);
    if (idx + 3 < n) v = *(const int4*)&in[idx];
    else {
        if (idx < n)     v.x = in[idx];
        if (idx + 1 < n) v.y = in[idx + 1];
        if (idx + 2 < n) v.z = in[idx + 2];
        if (idx + 3 < n) v.w = in[idx + 3];
    }
    // fused: dinv = rsqrt(deg + 1)  (+1 self-loop; always > 0)
    if (idx + 3 < n) {
        *(float4*)&dinv[idx] = make_float4(rsqrtf((float)v.x + 1.0f),
                                           rsqrtf((float)v.y + 1.0f),
                                           rsqrtf((float)v.z + 1.0f),
                                           rsqrtf((float)v.w + 1.0f));
    } else {
        if (idx < n)     dinv[idx]     = rsqrtf((float)v.x + 1.0f);
        if (idx + 1 < n) dinv[idx + 1] = rsqrtf((float)v.y + 1.0f);
        if (idx + 2 < n) dinv[idx + 2] = rsqrtf((float)v.z + 1.0f);
        if (idx + 3 < n) dinv[idx + 3] = rsqrtf((float)v.w + 1.0f);
    }
    int s1 = v.x, s2 = s1 + v.y, s3 = s2 + v.z, s4 = s3 + v.w;
    sdata[t] = s4;
    __syncthreads();
    for (int off = 1; off < 256; off <<= 1) {
        int val = (t >= off) ? sdata[t - off] : 0;
        __syncthreads();
        sdata[t] += val;
        __syncthreads();
    }
    int prev = sdata[t] - s4;
    if (idx < n)     out[idx]     = prev;
    if (idx + 1 < n) out[idx + 1] = prev + s1;
    if (idx + 2 < n) out[idx + 2] = prev + s2;
    if (idx + 3 < n) out[idx + 3] = prev + s3;
    if (t == 255) tilesums[blockIdx.x] = sdata[255];
}

__global__ void scan2_kernel(int* __restrict__ ts, int nt) {
    __shared__ int sdata[256];
    int t = threadIdx.x;
    int v = (t < nt) ? ts[t] : 0;
    sdata[t] = v;
    __syncthreads();
    for (int off = 1; off < 256; off <<= 1) {
        int val = (t >= off) ? sdata[t - off] : 0;
        __syncthreads();
        sdata[t] += val;
        __syncthreads();
    }
    if (t < nt) ts[t] = sdata[t] - v;  // exclusive
}

__global__ void scan3_kernel(int* __restrict__ row_ptr, int* __restrict__ cursor,
                             const int* __restrict__ ts, int n, int total) {
    int i = blockIdx.x * blockDim.x + threadIdx.x;
    if (i == 0) row_ptr[n] = total;
    if (i < n) {
        int rp = row_ptr[i] + ts[i >> 10];
        row_ptr[i] = rp;
        cursor[i] = rp;
    }
}

// Grouped CSR placement, coalesced int4 reads of src+dst; cursor atomics and
// csr_src writes stay in one XCD's L2 region.
__global__ __launch_bounds__(256) void csr_build_grouped_kernel(
    const int* __restrict__ src, const int* __restrict__ dst,
    int* __restrict__ cursor, int* __restrict__ csr_src, int E, int gsz)
{
    int g = blockIdx.x & (NGROUPS - 1);
    int bi = blockIdx.x / NGROUPS;
    int bpg = gridDim.x / NGROUPS;
    int lo = g * gsz, hi = lo + gsz;
    int E4 = E & ~3;
    int stride = bpg * 256 * 4;
    for (int i = (bi * 256 + threadIdx.x) * 4; i < E4; i += stride) {
        int4 d = *(const int4*)&dst[i];
        int4 s = *(const int4*)&src[i];
        if (d.x >= lo && d.x < hi) csr_src[atomicAdd(&cursor[d.x], 1)] = s.x;
        if (d.y >= lo && d.y < hi) csr_src[atomicAdd(&cursor[d.y], 1)] = s.y;
        if (d.z >= lo && d.z < hi) csr_src[atomicAdd(&cursor[d.z], 1)] = s.z;
        if (d.w >= lo && d.w < hi) csr_src[atomicAdd(&cursor[d.w], 1)] = s.w;
    }
    if (bi == 0 && threadIdx.x < (E & 3)) {
        int i = E4 + threadIdx.x;
        int d = dst[i];
        if (d >= lo && d < hi) csr_src[atomicAdd(&cursor[d], 1)] = src[i];
    }
}

// W[128][OC] f32 -> fragment-ordered bf16: wfrag[kk][ct][lane][e],
// element = W[kk*32 + (lane>>4)*8 + e][ct*16 + (lane&15)]
template <int OC>
__global__ void wreorder_kernel(const float* __restrict__ W, ushort* __restrict__ wfrag) {
    constexpr int NCT = OC / 16;
    int t = blockIdx.x * 256 + threadIdx.x;
    if (t >= 4 * NCT * 64) return;
    int lane = t & 63;
    int rest = t >> 6;
    int ct = rest % NCT;
    int kk = rest / NCT;
    int col = ct * 16 + (lane & 15);
    int krow = kk * 32 + (lane >> 4) * 8;
    ushort tmp[8];
    #pragma unroll
    for (int e = 0; e < 8; ++e)
        tmp[e] = f2bf(W[(size_t)(krow + e) * OC + col]);
    uint4 st;
    st.x = (uint)tmp[0] | ((uint)tmp[1] << 16);
    st.y = (uint)tmp[2] | ((uint)tmp[3] << 16);
    st.z = (uint)tmp[4] | ((uint)tmp[5] << 16);
    st.w = (uint)tmp[6] | ((uint)tmp[7] << 16);
    *(uint4*)&wfrag[(size_t)t * 8] = st;
}

// Y[N][OC] bf16 = dinv[row] * (A @ W) via mfma_f32_16x16x32_bf16. No LDS.
// A-frag: row = lane&15, k = kk*32 + (lane>>4)*8 + j. C/D: col=lane&15,
// row=(lane>>4)*4+reg. BN_IN: A = relu(bf16_in*sc[k]+sh[k]) in f32 -> bf16.
template <int OC, bool BN_IN>
__global__ __launch_bounds__(256) void mfma_gemm_kernel(
    const void* __restrict__ Xv, const ushort* __restrict__ wfrag,
    ushort* __restrict__ Y, const float* __restrict__ dinv,
    const float* __restrict__ sc, const float* __restrict__ sh, int N)
{
    constexpr int NCT = OC / 16;
    int wave = (blockIdx.x * 256 + threadIdx.x) >> 6;
    int lane = threadIdx.x & 63;
    int row16 = wave * 16;
    if (row16 >= N) return;
    int r = lane & 15;
    int g = lane >> 4;
    int row = row16 + r;  // N % 16 == 0 -> always < N

    float4v acc[NCT];
    #pragma unroll
    for (int ct = 0; ct < NCT; ++ct) acc[ct] = (float4v){0.f, 0.f, 0.f, 0.f};

    const short8v* wf = (const short8v*)wfrag;

    #pragma unroll
    for (int kk = 0; kk < 4; ++kk) {
        int k0 = kk * 32 + g * 8;
        short8v a;
        if constexpr (!BN_IN) {
            const float* xp = (const float*)Xv + (size_t)row * 128 + k0;
            float4 x0 = *(const float4*)xp;
            float4 x1 = *(const float4*)(xp + 4);
            a[0] = (short)f2bf(x0.x); a[1] = (short)f2bf(x0.y);
            a[2] = (short)f2bf(x0.z); a[3] = (short)f2bf(x0.w);
            a[4] = (short)f2bf(x1.x); a[5] = (short)f2bf(x1.y);
            a[6] = (short)f2bf(x1.z); a[7] = (short)f2bf(x1.w);
        } else {
            const ushort* xp = (const ushort*)Xv + (size_t)row * 128 + k0;
            uint4 v = *(const uint4*)xp;
            float4 s0 = *(const float4*)&sc[k0];
            float4 s1 = *(const float4*)&sc[k0 + 4];
            float4 h0 = *(const float4*)&sh[k0];
            float4 h1 = *(const float4*)&sh[k0 + 4];
            a[0] = (short)f2bf(fmaxf(fmaf(bf2f((ushort)(v.x & 0xffff)), s0.x, h0.x), 0.f));
            a[1] = (short)f2bf(fmaxf(fmaf(bf2f((ushort)(v.x >> 16)),    s0.y, h0.y), 0.f));
            a[2] = (short)f2bf(fmaxf(fmaf(bf2f((ushort)(v.y & 0xffff)), s0.z, h0.z), 0.f));
            a[3] = (short)f2bf(fmaxf(fmaf(bf2f((ushort)(v.y >> 16)),    s0.w, h0.w), 0.f));
            a[4] = (short)f2bf(fmaxf(fmaf(bf2f((ushort)(v.z & 0xffff)), s1.x, h1.x), 0.f));
            a[5] = (short)f2bf(fmaxf(fmaf(bf2f((ushort)(v.z >> 16)),    s1.y, h1.y), 0.f));
            a[6] = (short)f2bf(fmaxf(fmaf(bf2f((ushort)(v.w & 0xffff)), s1.z, h1.z), 0.f));
            a[7] = (short)f2bf(fmaxf(fmaf(bf2f((ushort)(v.w >> 16)),    s1.w, h1.w), 0.f));
        }
        #pragma unroll
        for (int ct = 0; ct < NCT; ++ct) {
            short8v b = wf[((size_t)(kk * NCT + ct)) * 64 + lane];
            acc[ct] = __builtin_amdgcn_mfma_f32_16x16x32_bf16(a, b, acc[ct], 0, 0, 0);
        }
    }
    float di[4];
    #pragma unroll
    for (int i = 0; i < 4; ++i) di[i] = dinv[row16 + g * 4 + i];
    #pragma unroll
    for (int ct = 0; ct < NCT; ++ct) {
        #pragma unroll
        for (int i = 0; i < 4; ++i) {
            int orow = row16 + g * 4 + i;
            Y[(size_t)orow * OC + ct * 16 + r] = f2bf(acc[ct][i] * di[i]);
        }
    }
}

// h' rows pre-scaled by dinv[src]. out[d] = dinv[d]*(sum_e h'[src_e] + h'[d]).
// One wave per node, PAR edges in flight, 2x unrolled -> 2 independent 1KB
// gathers outstanding per iteration. Self-row load hoisted above the loop.
template <int C, bool OUT_BF16>
__global__ __launch_bounds__(256) void aggregate_kernel(
    const ushort* __restrict__ h, const int* __restrict__ row_ptr,
    const int* __restrict__ csr_src, const float* __restrict__ dinv,
    void* __restrict__ outv, int N)
{
    constexpr int TPN = C / 8;     // lanes per row slice: 16 (C=128) / 8 (C=64)
    constexpr int PAR = 64 / TPN;  // edges in flight (per unroll step): 4 / 8
    int wid = (blockIdx.x * 256 + threadIdx.x) >> 6;
    if (wid >= N) return;
    int lane = threadIdx.x & 63;
    int part = lane / TPN;
    int c0 = (lane % TPN) * 8;
    float acc[8] = {0.f, 0.f, 0.f, 0.f, 0.f, 0.f, 0.f, 0.f};

    // hoist self-row load (only part 0 contributes it)
    uint4 vself = make_uint4(0u, 0u, 0u, 0u);
    if (part == 0) vself = *(const uint4*)&h[(size_t)wid * C + c0];

    int e = row_ptr[wid] + part;
    int e1 = row_ptr[wid + 1];
    // 2x unrolled: two independent index+gather chains per iteration
    for (; e + PAR < e1; e += 2 * PAR) {
        int s0 = csr_src[e];
        int s1 = csr_src[e + PAR];
        uint4 v0 = *(const uint4*)&h[(size_t)s0 * C + c0];
        uint4 v1 = *(const uint4*)&h[(size_t)s1 * C + c0];
        acc[0] += bf2f((ushort)(v0.x & 0xffff)) + bf2f((ushort)(v1.x & 0xffff));
        acc[1] += bf2f((ushort)(v0.x >> 16))    + bf2f((ushort)(v1.x >> 16));
        acc[2] += bf2f((ushort)(v0.y & 0xffff)) + bf2f((ushort)(v1.y & 0xffff));
        acc[3] += bf2f((ushort)(v0.y >> 16))    + bf2f((ushort)(v1.y >> 16));
        acc[4] += bf2f((ushort)(v0.z & 0xffff)) + bf2f((ushort)(v1.z & 0xffff));
        acc[5] += bf2f((ushort)(v0.z >> 16))    + bf2f((ushort)(v1.z >> 16));
        acc[6] += bf2f((ushort)(v0.w & 0xffff)) + bf2f((ushort)(v1.w & 0xffff));
        acc[7] += bf2f((ushort)(v0.w >> 16))    + bf2f((ushort)(v1.w >> 16));
    }
    if (e < e1) {
        int s = csr_src[e];
        uint4 v = *(const uint4*)&h[(size_t)s * C + c0];
        acc[0] += bf2f((ushort)(v.x & 0xffff));
        acc[1] += bf2f((ushort)(v.x >> 16));
        acc[2] += bf2f((ushort)(v.y & 0xffff));
        acc[3] += bf2f((ushort)(v.y >> 16));
        acc[4] += bf2f((ushort)(v.z & 0xffff));
        acc[5] += bf2f((ushort)(v.z >> 16));
        acc[6] += bf2f((ushort)(v.w & 0xffff));
        acc[7] += bf2f((ushort)(v.w >> 16));
    }
    if (part == 0) {
        acc[0] += bf2f((ushort)(vself.x & 0xffff));
        acc[1] += bf2f((ushort)(vself.x >> 16));
        acc[2] += bf2f((ushort)(vself.y & 0xffff));
        acc[3] += bf2f((ushort)(vself.y >> 16));
        acc[4] += bf2f((ushort)(vself.z & 0xffff));
        acc[5] += bf2f((ushort)(vself.z >> 16));
        acc[6] += bf2f((ushort)(vself.w & 0xffff));
        acc[7] += bf2f((ushort)(vself.w >> 16));
    }
    #pragma unroll
    for (int off = TPN; off < 64; off <<= 1) {
        #pragma unroll
        for (int j = 0; j < 8; ++j)
            acc[j] += __shfl_xor(acc[j], off, 64);
    }
    if (part == 0) {
        float dd = dinv[wid];
        #pragma unroll
        for (int j = 0; j < 8; ++j) acc[j] *= dd;
        if constexpr (OUT_BF16) {
            ushort* out = (ushort*)outv;
            uint4 st;
            st.x = (uint)f2bf(acc[0]) | ((uint)f2bf(acc[1]) << 16);
            st.y = (uint)f2bf(acc[2]) | ((uint)f2bf(acc[3]) << 16);
            st.z = (uint)f2bf(acc[4]) | ((uint)f2bf(acc[5]) << 16);
            st.w = (uint)f2bf(acc[6]) | ((uint)f2bf(acc[7]) << 16);
            *(uint4*)&out[(size_t)wid * C + c0] = st;
        } else {
            float* out = (float*)outv;
            *(float4*)&out[(size_t)wid * C + c0] =
                make_float4(acc[0], acc[1], acc[2], acc[3]);
            *(float4*)&out[(size_t)wid * C + c0 + 4] =
                make_float4(acc[4], acc[5], acc[6], acc[7]);
        }
    }
}

// Per-channel sum & sumsq over bf16 rows -> sums[0..C)=sum, sums[C..2C)=sumsq
template <int C>
__global__ __launch_bounds__(256) void stats_bf16_kernel(const ushort* __restrict__ h,
                                                         float* __restrict__ sums, int N)
{
    constexpr int CG = C / 8;
    constexpr int RPB = 256 / CG;
    __shared__ float red[RPB][CG][16];
    int tid = threadIdx.x;
    int cg = tid % CG, rg = tid / CG;
    int c0 = cg * 8;
    float s[8] = {0.f,0.f,0.f,0.f,0.f,0.f,0.f,0.f};
    float q[8] = {0.f,0.f,0.f,0.f,0.f,0.f,0.f,0.f};
    for (int r = blockIdx.x * RPB + rg; r < N; r += gridDim.x * RPB) {
        uint4 v = *(const uint4*)&h[(size_t)r * C + c0];
        float f0 = bf2f((ushort)(v.x & 0xffff)), f1 = bf2f((ushort)(v.x >> 16));
        float f2 = bf2f((ushort)(v.y & 0xffff)), f3 = bf2f((ushort)(v.y >> 16));
        float f4 = bf2f((ushort)(v.z & 0xffff)), f5 = bf2f((ushort)(v.z >> 16));
        float f6 = bf2f((ushort)(v.w & 0xffff)), f7 = bf2f((ushort)(v.w >> 16));
        s[0]+=f0; s[1]+=f1; s[2]+=f2; s[3]+=f3; s[4]+=f4; s[5]+=f5; s[6]+=f6; s[7]+=f7;
        q[0]=fmaf(f0,f0,q[0]); q[1]=fmaf(f1,f1,q[1]); q[2]=fmaf(f2,f2,q[2]); q[3]=fmaf(f3,f3,q[3]);
        q[4]=fmaf(f4,f4,q[4]); q[5]=fmaf(f5,f5,q[5]); q[6]=fmaf(f6,f6,q[6]); q[7]=fmaf(f7,f7,q[7]);
    }
    #pragma unroll
    for (int j = 0; j < 8; ++j) { red[rg][cg][j] = s[j]; red[rg][cg][8 + j] = q[j]; }
    __syncthreads();
    if (rg == 0) {
        float a[16];
        #pragma unroll
        for (int i = 0; i < 16; ++i) a[i] = red[0][cg][i];
        for (int r2 = 1; r2 < RPB; ++r2)
            #pragma unroll
            for (int i = 0; i < 16; ++i) a[i] += red[r2][cg][i];
        #pragma unroll
        for (int j = 0; j < 8; ++j) {
            atomicAdd(&sums[c0 + j], a[j]);
            atomicAdd(&sums[C + c0 + j], a[8 + j]);
        }
    }
}

// Per-channel sum & sumsq over f32 rows (for agg2)
template <int C>
__global__ __launch_bounds__(256) void stats_f32_kernel(const float* __restrict__ h,
                                                        float* __restrict__ sums, int N)
{
    constexpr int CG = C / 4;
    constexpr int RPB = 256 / CG;
    __shared__ float red[RPB][CG][8];
    int tid = threadIdx.x;
    int cg = tid % CG, rg = tid / CG;
    int c0 = cg * 4;
    float4 s = make_float4(0.f, 0.f, 0.f, 0.f);
    float4 q = make_float4(0.f, 0.f, 0.f, 0.f);
    for (int r = blockIdx.x * RPB + rg; r < N; r += gridDim.x * RPB) {
        float4 v = *(const float4*)&h[(size_t)r * C + c0];
        s.x += v.x; s.y += v.y; s.z += v.z; s.w += v.w;
        q.x = fmaf(v.x, v.x, q.x); q.y = fmaf(v.y, v.y, q.y);
        q.z = fmaf(v.z, v.z, q.z); q.w = fmaf(v.w, v.w, q.w);
    }
    float* rr = red[rg][cg];
    rr[0] = s.x; rr[1] = s.y; rr[2] = s.z; rr[3] = s.w;
    rr[4] = q.x; rr[5] = q.y; rr[6] = q.z; rr[7] = q.w;
    __syncthreads();
    if (rg == 0) {
        float a[8];
        #pragma unroll
        for (int i = 0; i < 8; ++i) a[i] = red[0][cg][i];
        for (int r2 = 1; r2 < RPB; ++r2)
            #pragma unroll
            for (int i = 0; i < 8; ++i) a[i] += red[r2][cg][i];
        #pragma unroll
        for (int j = 0; j < 4; ++j) {
            atomicAdd(&sums[c0 + j], a[j]);
            atomicAdd(&sums[C + c0 + j], a[4 + j]);
        }
    }
}

__global__ void bnprep_kernel(const float* __restrict__ stats, const float* __restrict__ gamma,
                              const float* __restrict__ beta, float* __restrict__ sc,
                              float* __restrict__ sh, int C, int N) {
    int c = threadIdx.x;
    if (c < C) {
        float invN = 1.0f / (float)N;
        float mu = stats[c] * invN;
        float var = stats[C + c] * invN - mu * mu;
        float s = rsqrtf(var + BN_EPS) * gamma[c];
        sc[c] = s;
        sh[c] = beta[c] - mu * s;
    }
}

template <int C>
__global__ void bn_apply_kernel(const float* __restrict__ in, float* __restrict__ out,
                                const float* __restrict__ sc, const float* __restrict__ sh,
                                int N)
{
    int total = N * (C / 4);
    int i = blockIdx.x * blockDim.x + threadIdx.x;
    int stride = gridDim.x * blockDim.x;
    for (; i < total; i += stride) {
        int c0 = (i * 4) % C;
        float4 v = *(const float4*)&in[(size_t)i * 4];
        float4 s = *(const float4*)&sc[c0];
        float4 h = *(const float4*)&sh[c0];
        v.x = fmaf(v.x, s.x, h.x);
        v.y = fmaf(v.y, s.y, h.y);
        v.z = fmaf(v.z, s.z, h.z);
        v.w = fmaf(v.w, s.w, h.w);
        *(float4*)&out[(size_t)i * 4] = v;
    }
}

extern "C" void kernel_launch(void* const* d_in, const int* in_sizes, int n_in,
                              void* d_out, int out_size, void* d_ws, size_t ws_size,
                              hipStream_t stream) {
    const float* x      = (const float*)d_in[0];
    const int*   ei     = (const int*)d_in[1];
    const float* W1     = (const float*)d_in[2];
    // d_in[3] = b1: cancels in BN1 -> skipped
    const float* gamma1 = (const float*)d_in[4];
    const float* beta1  = (const float*)d_in[5];
    const float* W2     = (const float*)d_in[6];
    // d_in[7] = b2: cancels in BN2 -> skipped
    const float* gamma2 = (const float*)d_in[8];
    const float* beta2  = (const float*)d_in[9];

    const int N = in_sizes[0] / IN_C;   // 100000 (divisible by 16)
    const int E = in_sizes[1] / 2;      // 1600000
    const int* src = ei;
    const int* dst = ei + E;
    const int gsz = (N + NGROUPS - 1) / NGROUPS;  // 12500

    float* ws     = (float*)d_ws;
    float* stats1 = ws;                  // 256
    float* stats2 = ws + 256;            // 128
    float* sc1    = ws + 384;            // 128
    float* sh1    = ws + 512;            // 128
    float* sc2    = ws + 640;            // 128 (64 used)
    float* sh2    = ws + 768;            // 128 (64 used)
    float* dinv   = ws + 896;            // N
    int*   deg    = (int*)(dinv + N);    // N (aliased as cursor after scan)
    int*   cursor = deg;
    int*   row_ptr = deg + N;            // N+16
    int*   tilesums = row_ptr + N + 16;  // 256
    int*   csr_src = tilesums + 256;     // E
    ushort* wfrag1 = (ushort*)(csr_src + E);        // 16384 bf16
    ushort* wfrag2 = wfrag1 + 16384;                // 8192 bf16
    ushort* h1     = wfrag2 + 8192;                 // N*128 bf16 (pre-scaled by dinv)
    ushort* bufB   = h1 + (size_t)N * HID_C;        // N*128 bf16
    ushort* h2     = bufB + (size_t)N * HID_C;      // N*64 bf16 (pre-scaled by dinv)
    float*  agg2   = (float*)(h2 + (size_t)N * OUT_C2);  // N*64 f32

    const int numTiles = (N + 1023) / 1024;

    init_kernel<<<(N + 255) / 256, 256, 0, stream>>>(ws, deg, N);
    degree_grouped_kernel<<<2048, 256, 0, stream>>>(dst, deg, E, gsz);
    scan1_kernel<<<numTiles, 256, 0, stream>>>(deg, row_ptr, tilesums, dinv, N);
    scan2_kernel<<<1, 256, 0, stream>>>(tilesums, numTiles);
    scan3_kernel<<<(N + 255) / 256, 256, 0, stream>>>(row_ptr, cursor, tilesums, N, E);
    csr_build_grouped_kernel<<<2048, 256, 0, stream>>>(src, dst, cursor, csr_src, E, gsz);

    wreorder_kernel<HID_C><<<8, 256, 0, stream>>>(W1, wfrag1);
    wreorder_kernel<OUT_C2><<<4, 256, 0, stream>>>(W2, wfrag2);

    // Layer 1: h1 = bf16(dinv * (x @ W1)); bufB = aggregate(h1) (bf16)
    mfma_gemm_kernel<HID_C, false><<<(N / 16 + 3) / 4, 256, 0, stream>>>(
        x, wfrag1, h1, dinv, nullptr, nullptr, N);
    aggregate_kernel<HID_C, true><<<(N + 3) / 4, 256, 0, stream>>>(
        h1, row_ptr, csr_src, dinv, bufB, N);
    stats_bf16_kernel<HID_C><<<256, 256, 0, stream>>>(bufB, stats1, N);
    bnprep_kernel<<<1, 256, 0, stream>>>(stats1, gamma1, beta1, sc1, sh1, HID_C, N);

    // Layer 2: h2 = bf16(dinv * (relu(bn1(bufB)) @ W2)); agg2 = aggregate(h2) (f32)
    mfma_gemm_kernel<OUT_C2, true><<<(N / 16 + 3) / 4, 256, 0, stream>>>(
        bufB, wfrag2, h2, dinv, sc1, sh1, N);
    aggregate_kernel<OUT_C2, false><<<(N + 3) / 4, 256, 0, stream>>>(
        h2, row_ptr, csr_src, dinv, agg2, N);
    stats_f32_kernel<OUT_C2><<<256, 256, 0, stream>>>(agg2, stats2, N);
    bnprep_kernel<<<1, 256, 0, stream>>>(stats2, gamma2, beta2, sc2, sh2, OUT_C2, N);

    bn_apply_kernel<OUT_C2><<<2048, 256, 0, stream>>>(agg2, (float*)d_out, sc2, sh2, N);
}